// Round 1
// baseline (13886.931 us; speedup 1.0000x reference)
//
#include <hip/hip_runtime.h>
#include <hip/hip_bf16.h>
#include <math.h>

// Problem constants
#define BB 128
#define SS 100
#define DD 512
#define HH 8
#define DHH 64
#define DFFF 2048
#define RR 199          // 2S-1
#define MM (BB*SS)      // 12800
#define NLAYERS 6
#define SCALE_ 0.125f

// ---------------------------------------------------------------------------
// Embedding + sinusoidal positional encoding:  src[b,s,:] = emb[id] + pe(s)
// grid = B*S blocks, block = 128 threads (4 dims each)
__global__ void embed_kernel(const int* __restrict__ ids, const float* __restrict__ emb,
                             float* __restrict__ src) {
    int r  = blockIdx.x;          // b*S+s
    int s  = r % SS;
    int id = ids[r];
    int d0 = threadIdx.x * 4;
    const float c = logf(10000.0f) / 512.0f;
    #pragma unroll
    for (int jj = 0; jj < 4; jj++) {
        int d  = d0 + jj;
        int j2 = d & ~1;
        float freq = expf(-(float)j2 * c);
        float ang  = (float)s * freq;
        float pe   = (d & 1) ? cosf(ang) : sinf(ang);
        src[r * DD + d] = emb[id * DD + d] + pe;
    }
}

// ---------------------------------------------------------------------------
// k_pos = sinusoid(rel) @ Wpos  -> (199, 512)
// grid = 199 blocks, block = 512 threads
__global__ void kpos_kernel(const float* __restrict__ Wpos, float* __restrict__ kp) {
    int r = blockIdx.x;           // 0..198
    float p = (float)(SS - 1 - r);  // 99 .. -99
    __shared__ float pe[DD];
    int t = threadIdx.x;
    const float c = logf(10000.0f) / 512.0f;
    {
        int j2 = t & ~1;
        float freq = expf(-(float)j2 * c);
        float ang  = p * freq;
        pe[t] = (t & 1) ? cosf(ang) : sinf(ang);
    }
    __syncthreads();
    float acc = 0.0f;
    for (int k = 0; k < DD; k++) acc += pe[k] * Wpos[k * DD + t];
    kp[r * DD + t] = acc;
}

// ---------------------------------------------------------------------------
// Generic fp32 GEMM: C[M,N] = act(A[M,K] @ W[K,N] + bias)
// BM=128, BN=64, BK=16; 256 threads, 8x4 micro-tile per thread.
// ACT: 0 none, 1 relu, 2 tanh, 3 sigmoid
template<int ACT>
__global__ __launch_bounds__(256) void gemm_kernel(const float* __restrict__ A,
                                                   const float* __restrict__ W,
                                                   const float* __restrict__ bias,
                                                   float* __restrict__ C,
                                                   int M, int N, int K) {
    __shared__ float As[16][136];   // [k][m], padded
    __shared__ float Ws[16][72];    // [k][n], padded
    int t  = threadIdx.x;
    int tx = t & 15;      // n micro index
    int ty = t >> 4;      // m micro index (0..15)
    int m0 = blockIdx.y * 128;
    int n0 = blockIdx.x * 64;

    float acc[8][4];
    #pragma unroll
    for (int i = 0; i < 8; i++)
        #pragma unroll
        for (int j = 0; j < 4; j++) acc[i][j] = 0.0f;

    int arow = t >> 2;            // 0..63
    int acol = (t & 3) * 4;       // 0..12
    int wrow = t >> 4;            // 0..15
    int wcol = (t & 15) * 4;      // 0..60

    for (int k0 = 0; k0 < K; k0 += 16) {
        float4 a0 = *(const float4*)(A + (size_t)(m0 + arow) * K + k0 + acol);
        float4 a1 = *(const float4*)(A + (size_t)(m0 + arow + 64) * K + k0 + acol);
        float4 w0 = *(const float4*)(W + (size_t)(k0 + wrow) * N + n0 + wcol);
        __syncthreads();
        As[acol + 0][arow] = a0.x; As[acol + 1][arow] = a0.y;
        As[acol + 2][arow] = a0.z; As[acol + 3][arow] = a0.w;
        As[acol + 0][arow + 64] = a1.x; As[acol + 1][arow + 64] = a1.y;
        As[acol + 2][arow + 64] = a1.z; As[acol + 3][arow + 64] = a1.w;
        *(float4*)&Ws[wrow][wcol] = w0;
        __syncthreads();
        #pragma unroll
        for (int kk = 0; kk < 16; kk++) {
            float areg[8], wreg[4];
            *(float4*)&areg[0] = *(const float4*)&As[kk][ty * 8];
            *(float4*)&areg[4] = *(const float4*)&As[kk][ty * 8 + 4];
            *(float4*)&wreg[0] = *(const float4*)&Ws[kk][tx * 4];
            #pragma unroll
            for (int i = 0; i < 8; i++)
                #pragma unroll
                for (int j = 0; j < 4; j++)
                    acc[i][j] += areg[i] * wreg[j];
        }
    }

    float bv[4] = {0.f, 0.f, 0.f, 0.f};
    if (bias) {
        float4 b4 = *(const float4*)(bias + n0 + tx * 4);
        bv[0] = b4.x; bv[1] = b4.y; bv[2] = b4.z; bv[3] = b4.w;
    }
    #pragma unroll
    for (int i = 0; i < 8; i++) {
        int m = m0 + ty * 8 + i;
        float o[4];
        #pragma unroll
        for (int j = 0; j < 4; j++) {
            float x = acc[i][j] + bv[j];
            if (ACT == 1) x = fmaxf(x, 0.0f);
            else if (ACT == 2) x = tanhf(x);
            else if (ACT == 3) x = 1.0f / (1.0f + expf(-x));
            o[j] = x;
        }
        float4 o4; o4.x = o[0]; o4.y = o[1]; o4.z = o[2]; o4.w = o[3];
        *(float4*)(C + (size_t)m * N + n0 + tx * 4) = o4;
    }
}

// ---------------------------------------------------------------------------
// Attention scores: att[b,h,i,j] = ((q+u)·k + (q+v)·kpos[99-i+j]) * SCALE,
// masked to -1e9 where j >= src_len[b].  One thread per score.
__global__ __launch_bounds__(256) void scores_kernel(const float* __restrict__ q,
                              const float* __restrict__ kv,
                              const float* __restrict__ kpos,
                              const float* __restrict__ u,
                              const float* __restrict__ v,
                              const int* __restrict__ src_len,
                              float* __restrict__ att) {
    int idx = blockIdx.x * 256 + threadIdx.x;   // ((b*8+h)*100+i)*100+j
    int j = idx % 100;
    int tmp = idx / 100;
    int i = tmp % 100;
    tmp /= 100;
    int h = tmp & 7;
    int b = tmp >> 3;

    const float4* qp = (const float4*)(q    + ((size_t)(b * SS + i) * HH + h) * DHH);
    const float4* up = (const float4*)(u    + h * DHH);
    const float4* vp = (const float4*)(v    + h * DHH);
    const float4* kp = (const float4*)(kv   + ((size_t)(b * SS + j) * HH + h) * 2 * DHH);
    const float4* pp = (const float4*)(kpos + ((size_t)(99 - i + j) * HH + h) * DHH);

    float cacc = 0.0f, pacc = 0.0f;
    #pragma unroll
    for (int d4 = 0; d4 < 16; d4++) {
        float4 qv = qp[d4], uu = up[d4], vv = vp[d4], kk = kp[d4], pv = pp[d4];
        cacc += (qv.x + uu.x) * kk.x + (qv.y + uu.y) * kk.y
              + (qv.z + uu.z) * kk.z + (qv.w + uu.w) * kk.w;
        pacc += (qv.x + vv.x) * pv.x + (qv.y + vv.y) * pv.y
              + (qv.z + vv.z) * pv.z + (qv.w + vv.w) * pv.w;
    }
    float s = (cacc + pacc) * SCALE_;
    if (j >= src_len[b]) s = -1e9f;
    att[idx] = s;
}

// ---------------------------------------------------------------------------
// Row softmax over last dim (100).  grid = B*H*S rows, block = 128.
__global__ void softmax_kernel(float* __restrict__ att) {
    int row = blockIdx.x;
    float* p = att + (size_t)row * 100;
    int t = threadIdx.x;
    float val = (t < 100) ? p[t] : -1e38f;
    float mx = val;
    #pragma unroll
    for (int o = 32; o > 0; o >>= 1) mx = fmaxf(mx, __shfl_down(mx, o));
    __shared__ float lm[2], lsum[2];
    if ((t & 63) == 0) lm[t >> 6] = mx;
    __syncthreads();
    float rowmax = fmaxf(lm[0], lm[1]);
    float e = (t < 100) ? expf(val - rowmax) : 0.0f;
    float sm = e;
    #pragma unroll
    for (int o = 32; o > 0; o >>= 1) sm += __shfl_down(sm, o);
    if ((t & 63) == 0) lsum[t >> 6] = sm;
    __syncthreads();
    float rowsum = lsum[0] + lsum[1];
    if (t < 100) p[t] = e / rowsum;
}

// ---------------------------------------------------------------------------
// out[b,i,h,:] = sum_j att[b,h,i,j] * vv[b,j,h,:]
// grid = B*H blocks, 256 threads; V staged in LDS.
__global__ __launch_bounds__(256) void av_kernel(const float* __restrict__ att,
                                                 const float* __restrict__ kv,
                                                 float* __restrict__ out) {
    int b = blockIdx.x >> 3;
    int h = blockIdx.x & 7;
    __shared__ float Vs[100 * 64];
    for (int idx = threadIdx.x; idx < 1600; idx += 256) {
        int j  = idx >> 4;
        int dh = (idx & 15) * 4;
        float4 vvv = *(const float4*)(kv + ((size_t)(b * SS + j) * HH + h) * 128 + 64 + dh);
        *(float4*)(Vs + j * 64 + dh) = vvv;
    }
    __syncthreads();
    int dh = threadIdx.x & 63;
    int w  = threadIdx.x >> 6;   // wave id 0..3
    const float* abase = att + ((size_t)(b * HH + h) * SS) * SS;
    for (int i = w; i < 100; i += 4) {
        const float* ar = abase + i * 100;
        float acc = 0.0f;
        for (int j = 0; j < 100; j++) acc += ar[j] * Vs[j * 64 + dh];
        out[(size_t)(b * SS + i) * DD + h * DHH + dh] = acc;
    }
}

// ---------------------------------------------------------------------------
// net = LayerNorm(src + a) * g + b.   grid = M rows, block = 128 (float4 each)
__global__ void ln_kernel(const float* __restrict__ x, const float* __restrict__ a,
                          const float* __restrict__ g, const float* __restrict__ bb,
                          float* __restrict__ out) {
    int r = blockIdx.x;
    int t = threadIdx.x;
    float4 xv = *(const float4*)(x + (size_t)r * DD + t * 4);
    float4 av = *(const float4*)(a + (size_t)r * DD + t * 4);
    float v0 = xv.x + av.x, v1 = xv.y + av.y, v2 = xv.z + av.z, v3 = xv.w + av.w;
    float sum = v0 + v1 + v2 + v3;
    float sq  = v0 * v0 + v1 * v1 + v2 * v2 + v3 * v3;
    #pragma unroll
    for (int o = 32; o > 0; o >>= 1) {
        sum += __shfl_down(sum, o);
        sq  += __shfl_down(sq, o);
    }
    __shared__ float ls[2], lq[2];
    if ((t & 63) == 0) { ls[t >> 6] = sum; lq[t >> 6] = sq; }
    __syncthreads();
    float S_ = ls[0] + ls[1], Q_ = lq[0] + lq[1];
    float m   = S_ / 512.0f;
    float var = Q_ / 512.0f - m * m;
    float rs  = rsqrtf(var + 1e-5f);
    float4 gv = *(const float4*)(g  + t * 4);
    float4 bv = *(const float4*)(bb + t * 4);
    float4 o4;
    o4.x = (v0 - m) * rs * gv.x + bv.x;
    o4.y = (v1 - m) * rs * gv.y + bv.y;
    o4.z = (v2 - m) * rs * gv.z + bv.z;
    o4.w = (v3 - m) * rs * gv.w + bv.w;
    *(float4*)(out + (size_t)r * DD + t * 4) = o4;
}

// ---------------------------------------------------------------------------
// src = src*(1-bg) + proj*bg   (float4 elementwise)
__global__ void combine_kernel(float* __restrict__ src, const float* __restrict__ bg,
                               const float* __restrict__ proj) {
    int idx = blockIdx.x * 256 + threadIdx.x;
    float4 s = ((const float4*)src)[idx];
    float4 g = ((const float4*)bg)[idx];
    float4 p = ((const float4*)proj)[idx];
    s.x = s.x * (1.0f - g.x) + p.x * g.x;
    s.y = s.y * (1.0f - g.y) + p.y * g.y;
    s.z = s.z * (1.0f - g.z) + p.z * g.z;
    s.w = s.w * (1.0f - g.w) + p.w * g.w;
    ((float4*)src)[idx] = s;
}

// ---------------------------------------------------------------------------
extern "C" void kernel_launch(void* const* d_in, const int* in_sizes, int n_in,
                              void* d_out, int out_size, void* d_ws, size_t ws_size,
                              hipStream_t stream) {
    const int*   ids     = (const int*)  d_in[0];
    const int*   src_len = (const int*)  d_in[1];
    const float* emb     = (const float*)d_in[2];
    const float* Wq      = (const float*)d_in[3];
    const float* Wkv     = (const float*)d_in[4];
    const float* Wpos    = (const float*)d_in[5];
    const float* Wout    = (const float*)d_in[6];
    const float* u       = (const float*)d_in[7];
    const float* v       = (const float*)d_in[8];
    const float* ng      = (const float*)d_in[9];
    const float* nb      = (const float*)d_in[10];
    const float* p1_w    = (const float*)d_in[11];
    const float* p1_b    = (const float*)d_in[12];
    const float* p2_w    = (const float*)d_in[13];
    const float* p2_b    = (const float*)d_in[14];
    const float* g1_w    = (const float*)d_in[15];
    const float* g1_b    = (const float*)d_in[16];
    const float* g2_w    = (const float*)d_in[17];
    const float* g2_b    = (const float*)d_in[18];

    float* src = (float*)d_out;           // (M, 512), evolves per layer

    // workspace layout (floats)
    float* ws   = (float*)d_ws;
    float* kpos = ws;                               // 199*512     = 101,888
    float* q    = kpos + (size_t)RR * DD;           // M*512       = 6,553,600
    float* kv   = q    + (size_t)MM * DD;           // M*1024      = 13,107,200
    float* t0   = kv   + (size_t)MM * 2 * DD;       // M*512
    float* t1   = t0   + (size_t)MM * DD;           // M*512
    float* ff   = t1   + (size_t)MM * DD;           // M*2048 (also holds att scores)
    float* att  = ff;                               // B*H*S*S = 10,240,000 <= M*2048

    // src = emb[ids] + sinusoid
    hipLaunchKernelGGL(embed_kernel, dim3(MM), dim3(128), 0, stream, ids, emb, src);
    // k_pos = sinusoid(rel) @ Wpos
    hipLaunchKernelGGL(kpos_kernel, dim3(RR), dim3(DD), 0, stream, Wpos, kpos);

    for (int layer = 0; layer < NLAYERS; layer++) {
        // q = src @ Wq          (M,512)
        hipLaunchKernelGGL((gemm_kernel<0>), dim3(DD / 64, MM / 128), dim3(256), 0, stream,
                           src, Wq, (const float*)nullptr, q, MM, DD, DD);
        // kv = src @ Wkv        (M,1024)
        hipLaunchKernelGGL((gemm_kernel<0>), dim3(2 * DD / 64, MM / 128), dim3(256), 0, stream,
                           src, Wkv, (const float*)nullptr, kv, MM, 2 * DD, DD);
        // attention
        hipLaunchKernelGGL(scores_kernel, dim3(BB * HH * SS * SS / 256), dim3(256), 0, stream,
                           q, kv, kpos, u, v, src_len, att);
        hipLaunchKernelGGL(softmax_kernel, dim3(BB * HH * SS), dim3(128), 0, stream, att);
        hipLaunchKernelGGL(av_kernel, dim3(BB * HH), dim3(256), 0, stream, att, kv, t0);
        // a = attn_out @ Wout   -> t1
        hipLaunchKernelGGL((gemm_kernel<0>), dim3(DD / 64, MM / 128), dim3(256), 0, stream,
                           t0, Wout, (const float*)nullptr, t1, MM, DD, DD);
        // net = LN(src + a)     -> t0
        hipLaunchKernelGGL(ln_kernel, dim3(MM), dim3(128), 0, stream, src, t1, ng, nb, t0);
        // h1 = relu(net @ p1_w + p1_b)  -> ff  (M,2048)
        hipLaunchKernelGGL((gemm_kernel<1>), dim3(DFFF / 64, MM / 128), dim3(256), 0, stream,
                           t0, p1_w, p1_b, ff, MM, DFFF, DD);
        // proj = tanh(h1 @ p2_w + p2_b) -> t1  (M,512)
        hipLaunchKernelGGL((gemm_kernel<2>), dim3(DD / 64, MM / 128), dim3(256), 0, stream,
                           ff, p2_w, p2_b, t1, MM, DD, DFFF);
        // hg = relu(net @ g1_w + g1_b)  -> q   (M,512)
        hipLaunchKernelGGL((gemm_kernel<1>), dim3(DD / 64, MM / 128), dim3(256), 0, stream,
                           t0, g1_w, g1_b, q, MM, DD, DD);
        // bg = sigmoid(hg @ g2_w + g2_b) -> kv (M,512)
        hipLaunchKernelGGL((gemm_kernel<3>), dim3(DD / 64, MM / 128), dim3(256), 0, stream,
                           q, g2_w, g2_b, kv, MM, DD, DD);
        // src = src*(1-bg) + proj*bg
        hipLaunchKernelGGL(combine_kernel, dim3(MM * DD / 4 / 256), dim3(256), 0, stream,
                           src, kv, t1);
    }
}

// Round 2
// 3863.511 us; speedup vs baseline: 3.5944x; 3.5944x over previous
//
#include <hip/hip_runtime.h>
#include <hip/hip_bf16.h>
#include <math.h>

// Problem constants
#define BB 128
#define SS 100
#define DD 512
#define HH 8
#define DHH 64
#define DFFF 2048
#define RR 199          // 2S-1
#define MM (BB*SS)      // 12800
#define NLAYERS 6
#define SCALE_ 0.125f

typedef __attribute__((ext_vector_type(8))) short bf16x8;
typedef __attribute__((ext_vector_type(4))) float floatx4;

__device__ inline unsigned short f2bf(float f) {
    union { float f; unsigned u; } c; c.f = f;
    unsigned r = c.u + 0x7FFFu + ((c.u >> 16) & 1u);   // round-to-nearest-even
    return (unsigned short)(r >> 16);
}

// ---------------------------------------------------------------------------
// Embedding + sinusoidal positional encoding:  src[b,s,:] = emb[id] + pe(s)
__global__ void embed_kernel(const int* __restrict__ ids, const float* __restrict__ emb,
                             float* __restrict__ src) {
    int r  = blockIdx.x;          // b*S+s
    int s  = r % SS;
    int id = ids[r];
    int d0 = threadIdx.x * 4;
    const float c = logf(10000.0f) / 512.0f;
    #pragma unroll
    for (int jj = 0; jj < 4; jj++) {
        int d  = d0 + jj;
        int j2 = d & ~1;
        float freq = expf(-(float)j2 * c);
        float ang  = (float)s * freq;
        float pe   = (d & 1) ? cosf(ang) : sinf(ang);
        src[r * DD + d] = emb[id * DD + d] + pe;
    }
}

// ---------------------------------------------------------------------------
// k_pos = sinusoid(rel) @ Wpos  -> (199, 512)  (fp32, runs once)
__global__ void kpos_kernel(const float* __restrict__ Wpos, float* __restrict__ kp) {
    int r = blockIdx.x;
    float p = (float)(SS - 1 - r);
    __shared__ float pe[DD];
    int t = threadIdx.x;
    const float c = logf(10000.0f) / 512.0f;
    {
        int j2 = t & ~1;
        float freq = expf(-(float)j2 * c);
        float ang  = p * freq;
        pe[t] = (t & 1) ? cosf(ang) : sinf(ang);
    }
    __syncthreads();
    float acc = 0.0f;
    for (int k = 0; k < DD; k++) acc += pe[k] * Wpos[k * DD + t];
    kp[r * DD + t] = acc;
}

// ---------------------------------------------------------------------------
// Weight transpose + bf16 convert:  Wt[n*K+k] = bf16(W[k*N+n])
__global__ void wtr_kernel(const float* __restrict__ W, unsigned short* __restrict__ Wt,
                           int K, int N) {
    int idx = blockIdx.x * 256 + threadIdx.x;
    if (idx >= K * N) return;
    int k = idx / N, n = idx - k * N;
    Wt[(size_t)n * K + k] = f2bf(W[idx]);
}

// ---------------------------------------------------------------------------
// bf16 MFMA GEMM: C[M,N] = act(A[M,K] @ B[K,N] + bias), B given transposed bf16 [N][K].
// BM=BN=128, BK=32. 256 threads = 4 waves, each wave a 64x64 block (4x4 frags 16x16x32).
// LDS chunk layout: chunk idx = (k/8)*128 + row, 8 bf16 per chunk (16B).
// ACT: 0 none, 1 relu, 2 tanh, 3 sigmoid
template<int ACT>
__global__ __launch_bounds__(256) void mgemm_kernel(const float* __restrict__ A,
                                                    const unsigned short* __restrict__ Bt,
                                                    const float* __restrict__ bias,
                                                    float* __restrict__ C,
                                                    int M, int N, int K) {
    __shared__ __align__(16) unsigned short As[128 * 32];
    __shared__ __align__(16) unsigned short Bs[128 * 32];
    int t = threadIdx.x;
    int lane = t & 63, wave = t >> 6;
    int wm = (wave & 1) * 64, wn = (wave >> 1) * 64;
    int quad = lane >> 4, l16 = lane & 15;
    int m0 = blockIdx.y * 128, n0 = blockIdx.x * 128;

    floatx4 acc[4][4];
    #pragma unroll
    for (int i = 0; i < 4; i++)
        #pragma unroll
        for (int j = 0; j < 4; j++)
            acc[i][j] = (floatx4){0.f, 0.f, 0.f, 0.f};

    int am = t >> 1, ak = (t & 1) * 16;   // A: 2 threads/row, 16 floats each
    int bn = t >> 1, bk = (t & 1) * 16;   // B: 2 threads/row, 16 bf16 each
    const float*          aptr = A  + (size_t)(m0 + am) * K + ak;
    const unsigned short* bptr = Bt + (size_t)(n0 + bn) * K + bk;

    for (int k0 = 0; k0 < K; k0 += 32) {
        float4 a0 = ((const float4*)(aptr + k0))[0];
        float4 a1 = ((const float4*)(aptr + k0))[1];
        float4 a2 = ((const float4*)(aptr + k0))[2];
        float4 a3 = ((const float4*)(aptr + k0))[3];
        uint4  b0 = ((const uint4*)(bptr + k0))[0];
        uint4  b1 = ((const uint4*)(bptr + k0))[1];
        __syncthreads();   // previous iter's frag reads done
        unsigned short pk[16];
        float av[16] = {a0.x, a0.y, a0.z, a0.w, a1.x, a1.y, a1.z, a1.w,
                        a2.x, a2.y, a2.z, a2.w, a3.x, a3.y, a3.z, a3.w};
        #pragma unroll
        for (int j = 0; j < 16; j++) pk[j] = f2bf(av[j]);
        *(uint4*)(As + (((ak >> 3)    ) * 128 + am) * 8) = *(uint4*)&pk[0];
        *(uint4*)(As + (((ak >> 3) + 1) * 128 + am) * 8) = *(uint4*)&pk[8];
        *(uint4*)(Bs + (((bk >> 3)    ) * 128 + bn) * 8) = b0;
        *(uint4*)(Bs + (((bk >> 3) + 1) * 128 + bn) * 8) = b1;
        __syncthreads();
        bf16x8 af[4], bfv[4];
        #pragma unroll
        for (int mf = 0; mf < 4; mf++)
            af[mf]  = *(const bf16x8*)(As + (quad * 128 + wm + mf * 16 + l16) * 8);
        #pragma unroll
        for (int nf = 0; nf < 4; nf++)
            bfv[nf] = *(const bf16x8*)(Bs + (quad * 128 + wn + nf * 16 + l16) * 8);
        #pragma unroll
        for (int mf = 0; mf < 4; mf++)
            #pragma unroll
            for (int nf = 0; nf < 4; nf++)
                acc[mf][nf] = __builtin_amdgcn_mfma_f32_16x16x32_bf16(
                                  af[mf], bfv[nf], acc[mf][nf], 0, 0, 0);
    }

    // epilogue: D col = lane&15, row = quad*4 + reg
    #pragma unroll
    for (int nf = 0; nf < 4; nf++) {
        int col = n0 + wn + nf * 16 + l16;
        float bv = bias ? bias[col] : 0.0f;
        #pragma unroll
        for (int mf = 0; mf < 4; mf++) {
            #pragma unroll
            for (int r = 0; r < 4; r++) {
                int row = m0 + wm + mf * 16 + quad * 4 + r;
                float x = acc[mf][nf][r] + bv;
                if (ACT == 1) x = fmaxf(x, 0.0f);
                else if (ACT == 2) x = tanhf(x);
                else if (ACT == 3) x = 1.0f / (1.0f + expf(-x));
                C[(size_t)row * N + col] = x;
            }
        }
    }
}

// ---------------------------------------------------------------------------
// Fused attention: one block per (b,h). Stages K,V,kpos head-slices in LDS,
// computes scores+mask+softmax+AV. fp32 throughout.
__global__ __launch_bounds__(256) void attn_kernel(const float* __restrict__ q,
                                                   const float* __restrict__ kv,
                                                   const float* __restrict__ kpos,
                                                   const float* __restrict__ u,
                                                   const float* __restrict__ v,
                                                   const int* __restrict__ len_,
                                                   float* __restrict__ out) {
    int b = blockIdx.x >> 3, h = blockIdx.x & 7;
    __shared__ float k_s[100 * 65];     // +1 pad -> 2-way conflicts (free)
    __shared__ float p_s[199 * 65];
    __shared__ float v_s[100 * 64];     // lane=d reads are 2-way (free)
    __shared__ float qu_s[4][64], qv_s[4][64];
    __shared__ float arow[4][128];
    int t = threadIdx.x, wave = t >> 6, lane = t & 63;

    for (int idx = t; idx < 100 * 64; idx += 256) {
        int j = idx >> 6, d = idx & 63;
        const float* kvp = kv + ((size_t)(b * SS + j) * HH + h) * 128;
        k_s[j * 65 + d] = kvp[d];
        v_s[j * 64 + d] = kvp[64 + d];
    }
    for (int idx = t; idx < RR * 64; idx += 256) {
        int r = idx >> 6, d = idx & 63;
        p_s[r * 65 + d] = kpos[(size_t)r * DD + h * 64 + d];
    }
    float u_r = u[h * 64 + lane];
    float v_r = v[h * 64 + lane];
    int len = len_[b];
    __syncthreads();

    for (int i = wave; i < 100; i += 4) {
        float qd = q[((size_t)(b * SS + i)) * DD + h * 64 + lane];
        qu_s[wave][lane] = qd + u_r;
        qv_s[wave][lane] = qd + v_r;
        // wave-internal LDS write->read: ordered by lgkmcnt, no barrier needed
        bool v2 = (lane + 64 < 100);
        int j1 = lane;
        int j2 = v2 ? lane + 64 : 99;
        int r1 = 99 - i + j1, r2 = 99 - i + j2;
        float s0 = 0.f, s1 = 0.f;
        for (int d = 0; d < 64; d++) {
            float quv = qu_s[wave][d], qvv = qv_s[wave][d];
            s0 += quv * k_s[j1 * 65 + d] + qvv * p_s[r1 * 65 + d];
            s1 += quv * k_s[j2 * 65 + d] + qvv * p_s[r2 * 65 + d];
        }
        s0 = (j1 < len) ? s0 * SCALE_ : -1e9f;
        s1 = (v2 && (lane + 64 < len)) ? s1 * SCALE_ : -1e9f;
        float mx = fmaxf(s0, v2 ? s1 : -3e38f);
        #pragma unroll
        for (int o = 32; o; o >>= 1) mx = fmaxf(mx, __shfl_xor(mx, o));
        float e0 = expf(s0 - mx);
        float e1 = v2 ? expf(s1 - mx) : 0.0f;
        float sm = e0 + e1;
        #pragma unroll
        for (int o = 32; o; o >>= 1) sm += __shfl_xor(sm, o);
        float inv = 1.0f / sm;
        arow[wave][lane] = e0 * inv;
        arow[wave][64 + lane] = e1 * inv;
        float acc = 0.f;
        for (int j = 0; j < 100; j++)
            acc += arow[wave][j] * v_s[j * 64 + lane];
        out[((size_t)(b * SS + i)) * DD + h * 64 + lane] = acc;
    }
}

// ---------------------------------------------------------------------------
// net = LayerNorm(src + a) * g + b
__global__ void ln_kernel(const float* __restrict__ x, const float* __restrict__ a,
                          const float* __restrict__ g, const float* __restrict__ bb,
                          float* __restrict__ out) {
    int r = blockIdx.x;
    int t = threadIdx.x;
    float4 xv = *(const float4*)(x + (size_t)r * DD + t * 4);
    float4 av = *(const float4*)(a + (size_t)r * DD + t * 4);
    float v0 = xv.x + av.x, v1 = xv.y + av.y, v2 = xv.z + av.z, v3 = xv.w + av.w;
    float sum = v0 + v1 + v2 + v3;
    float sq  = v0 * v0 + v1 * v1 + v2 * v2 + v3 * v3;
    #pragma unroll
    for (int o = 32; o > 0; o >>= 1) {
        sum += __shfl_down(sum, o);
        sq  += __shfl_down(sq, o);
    }
    __shared__ float ls[2], lq[2];
    if ((t & 63) == 0) { ls[t >> 6] = sum; lq[t >> 6] = sq; }
    __syncthreads();
    float S_ = ls[0] + ls[1], Q_ = lq[0] + lq[1];
    float m   = S_ / 512.0f;
    float var = Q_ / 512.0f - m * m;
    float rs  = rsqrtf(var + 1e-5f);
    float4 gv = *(const float4*)(g  + t * 4);
    float4 bv = *(const float4*)(bb + t * 4);
    float4 o4;
    o4.x = (v0 - m) * rs * gv.x + bv.x;
    o4.y = (v1 - m) * rs * gv.y + bv.y;
    o4.z = (v2 - m) * rs * gv.z + bv.z;
    o4.w = (v3 - m) * rs * gv.w + bv.w;
    *(float4*)(out + (size_t)r * DD + t * 4) = o4;
}

// ---------------------------------------------------------------------------
// src = src*(1-bg) + proj*bg
__global__ void combine_kernel(float* __restrict__ src, const float* __restrict__ bg,
                               const float* __restrict__ proj) {
    int idx = blockIdx.x * 256 + threadIdx.x;
    float4 s = ((const float4*)src)[idx];
    float4 g = ((const float4*)bg)[idx];
    float4 p = ((const float4*)proj)[idx];
    s.x = s.x * (1.0f - g.x) + p.x * g.x;
    s.y = s.y * (1.0f - g.y) + p.y * g.y;
    s.z = s.z * (1.0f - g.z) + p.z * g.z;
    s.w = s.w * (1.0f - g.w) + p.w * g.w;
    ((float4*)src)[idx] = s;
}

// ---------------------------------------------------------------------------
extern "C" void kernel_launch(void* const* d_in, const int* in_sizes, int n_in,
                              void* d_out, int out_size, void* d_ws, size_t ws_size,
                              hipStream_t stream) {
    const int*   ids     = (const int*)  d_in[0];
    const int*   src_len = (const int*)  d_in[1];
    const float* emb     = (const float*)d_in[2];
    const float* Wq      = (const float*)d_in[3];
    const float* Wkv     = (const float*)d_in[4];
    const float* Wpos    = (const float*)d_in[5];
    const float* Wout    = (const float*)d_in[6];
    const float* u       = (const float*)d_in[7];
    const float* v       = (const float*)d_in[8];
    const float* ng      = (const float*)d_in[9];
    const float* nb      = (const float*)d_in[10];
    const float* p1_w    = (const float*)d_in[11];
    const float* p1_b    = (const float*)d_in[12];
    const float* p2_w    = (const float*)d_in[13];
    const float* p2_b    = (const float*)d_in[14];
    const float* g1_w    = (const float*)d_in[15];
    const float* g1_b    = (const float*)d_in[16];
    const float* g2_w    = (const float*)d_in[17];
    const float* g2_b    = (const float*)d_in[18];

    float* src = (float*)d_out;           // (M, 512)

    // workspace layout
    float* ws   = (float*)d_ws;
    float* kpos = ws;                               // RR*DD
    float* q    = kpos + (size_t)RR * DD;           // M*512
    float* kv   = q    + (size_t)MM * DD;           // M*1024
    float* t0   = kv   + (size_t)MM * 2 * DD;       // M*512
    float* t1   = t0   + (size_t)MM * DD;           // M*512
    float* ff   = t1   + (size_t)MM * DD;           // M*2048
    unsigned short* wq_t   = (unsigned short*)(ff + (size_t)MM * DFFF);
    unsigned short* wkv_t  = wq_t   + 512 * 512;
    unsigned short* wout_t = wkv_t  + 1024 * 512;
    unsigned short* p1_t   = wout_t + 512 * 512;
    unsigned short* p2_t   = p1_t   + 2048 * 512;
    unsigned short* g1_t   = p2_t   + 512 * 2048;
    unsigned short* g2_t   = g1_t   + 512 * 512;

    // one-time (per call) prep
    hipLaunchKernelGGL(embed_kernel, dim3(MM), dim3(128), 0, stream, ids, emb, src);
    hipLaunchKernelGGL(kpos_kernel, dim3(RR), dim3(DD), 0, stream, Wpos, kpos);
    hipLaunchKernelGGL(wtr_kernel, dim3((512*512 +255)/256), dim3(256), 0, stream, Wq,   wq_t,   512, 512);
    hipLaunchKernelGGL(wtr_kernel, dim3((512*1024+255)/256), dim3(256), 0, stream, Wkv,  wkv_t,  512, 1024);
    hipLaunchKernelGGL(wtr_kernel, dim3((512*512 +255)/256), dim3(256), 0, stream, Wout, wout_t, 512, 512);
    hipLaunchKernelGGL(wtr_kernel, dim3((512*2048+255)/256), dim3(256), 0, stream, p1_w, p1_t,   512, 2048);
    hipLaunchKernelGGL(wtr_kernel, dim3((2048*512+255)/256), dim3(256), 0, stream, p2_w, p2_t,   2048, 512);
    hipLaunchKernelGGL(wtr_kernel, dim3((512*512 +255)/256), dim3(256), 0, stream, g1_w, g1_t,   512, 512);
    hipLaunchKernelGGL(wtr_kernel, dim3((512*512 +255)/256), dim3(256), 0, stream, g2_w, g2_t,   512, 512);

    for (int layer = 0; layer < NLAYERS; layer++) {
        hipLaunchKernelGGL((mgemm_kernel<0>), dim3(512/128,  MM/128), dim3(256), 0, stream,
                           src, wq_t, (const float*)nullptr, q, MM, 512, 512);
        hipLaunchKernelGGL((mgemm_kernel<0>), dim3(1024/128, MM/128), dim3(256), 0, stream,
                           src, wkv_t, (const float*)nullptr, kv, MM, 1024, 512);
        hipLaunchKernelGGL(attn_kernel, dim3(BB * HH), dim3(256), 0, stream,
                           q, kv, kpos, u, v, src_len, t0);
        hipLaunchKernelGGL((mgemm_kernel<0>), dim3(512/128,  MM/128), dim3(256), 0, stream,
                           t0, wout_t, (const float*)nullptr, t1, MM, 512, 512);
        hipLaunchKernelGGL(ln_kernel, dim3(MM), dim3(128), 0, stream, src, t1, ng, nb, t0);
        hipLaunchKernelGGL((mgemm_kernel<1>), dim3(2048/128, MM/128), dim3(256), 0, stream,
                           t0, p1_t, p1_b, ff, MM, 2048, 512);
        hipLaunchKernelGGL((mgemm_kernel<2>), dim3(512/128,  MM/128), dim3(256), 0, stream,
                           ff, p2_t, p2_b, t1, MM, 512, 2048);
        hipLaunchKernelGGL((mgemm_kernel<1>), dim3(512/128,  MM/128), dim3(256), 0, stream,
                           t0, g1_t, g1_b, q, MM, 512, 512);
        hipLaunchKernelGGL((mgemm_kernel<3>), dim3(512/128,  MM/128), dim3(256), 0, stream,
                           q, g2_t, g2_b, kv, MM, 512, 512);
        hipLaunchKernelGGL(combine_kernel, dim3(MM * DD / 4 / 256), dim3(256), 0, stream,
                           src, kv, t1);
    }
}

// Round 3
// 2864.732 us; speedup vs baseline: 4.8475x; 1.3486x over previous
//
#include <hip/hip_runtime.h>
#include <hip/hip_bf16.h>
#include <math.h>

// Problem constants
#define BB 128
#define SS 100
#define DD 512
#define HH 8
#define DHH 64
#define DFFF 2048
#define RR 199          // 2S-1
#define MM (BB*SS)      // 12800
#define NLAYERS 6
#define SCALE_ 0.125f

typedef __attribute__((ext_vector_type(8))) short bf16x8;
typedef __attribute__((ext_vector_type(4))) float floatx4;

__device__ inline unsigned short f2bf(float f) {
    union { float f; unsigned u; } c; c.f = f;
    unsigned r = c.u + 0x7FFFu + ((c.u >> 16) & 1u);   // round-to-nearest-even
    return (unsigned short)(r >> 16);
}
__device__ inline float bf2f(unsigned short h) {
    union { unsigned u; float f; } c; c.u = ((unsigned)h) << 16;
    return c.f;
}
// split fp32[8] into hi/lo bf16 fragments (error compensation)
__device__ inline void split8(const float* x, bf16x8& hi, bf16x8& lo) {
    #pragma unroll
    for (int i = 0; i < 8; i++) {
        unsigned short h_ = f2bf(x[i]);
        hi[i] = (short)h_;
        lo[i] = (short)f2bf(x[i] - bf2f(h_));
    }
}

// ---------------------------------------------------------------------------
// Embedding + sinusoidal positional encoding
__global__ void embed_kernel(const int* __restrict__ ids, const float* __restrict__ emb,
                             float* __restrict__ src) {
    int r  = blockIdx.x;
    int s  = r % SS;
    int id = ids[r];
    int d0 = threadIdx.x * 4;
    const float c = logf(10000.0f) / 512.0f;
    #pragma unroll
    for (int jj = 0; jj < 4; jj++) {
        int d  = d0 + jj;
        int j2 = d & ~1;
        float freq = expf(-(float)j2 * c);
        float ang  = (float)s * freq;
        float pe   = (d & 1) ? cosf(ang) : sinf(ang);
        src[r * DD + d] = emb[id * DD + d] + pe;
    }
}

// ---------------------------------------------------------------------------
// k_pos = sinusoid(rel) @ Wpos  -> (199, 512)
__global__ void kpos_kernel(const float* __restrict__ Wpos, float* __restrict__ kp) {
    int r = blockIdx.x;
    float p = (float)(SS - 1 - r);
    __shared__ float pe[DD];
    int t = threadIdx.x;
    const float c = logf(10000.0f) / 512.0f;
    {
        int j2 = t & ~1;
        float freq = expf(-(float)j2 * c);
        float ang  = p * freq;
        pe[t] = (t & 1) ? cosf(ang) : sinf(ang);
    }
    __syncthreads();
    float acc = 0.0f;
    for (int k = 0; k < DD; k++) acc += pe[k] * Wpos[k * DD + t];
    kp[r * DD + t] = acc;
}

// ---------------------------------------------------------------------------
// Weight transpose + bf16 convert
__global__ void wtr_kernel(const float* __restrict__ W, unsigned short* __restrict__ Wt,
                           int K, int N) {
    int idx = blockIdx.x * 256 + threadIdx.x;
    if (idx >= K * N) return;
    int k = idx / N, n = idx - k * N;
    Wt[(size_t)n * K + k] = f2bf(W[idx]);
}

// ---------------------------------------------------------------------------
// bf16 MFMA GEMM (unchanged from round 2)
template<int ACT>
__global__ __launch_bounds__(256) void mgemm_kernel(const float* __restrict__ A,
                                                    const unsigned short* __restrict__ Bt,
                                                    const float* __restrict__ bias,
                                                    float* __restrict__ C,
                                                    int M, int N, int K) {
    __shared__ __align__(16) unsigned short As[128 * 32];
    __shared__ __align__(16) unsigned short Bs[128 * 32];
    int t = threadIdx.x;
    int lane = t & 63, wave = t >> 6;
    int wm = (wave & 1) * 64, wn = (wave >> 1) * 64;
    int quad = lane >> 4, l16 = lane & 15;
    int m0 = blockIdx.y * 128, n0 = blockIdx.x * 128;

    floatx4 acc[4][4];
    #pragma unroll
    for (int i = 0; i < 4; i++)
        #pragma unroll
        for (int j = 0; j < 4; j++)
            acc[i][j] = (floatx4){0.f, 0.f, 0.f, 0.f};

    int am = t >> 1, ak = (t & 1) * 16;
    int bn = t >> 1, bk = (t & 1) * 16;
    const float*          aptr = A  + (size_t)(m0 + am) * K + ak;
    const unsigned short* bptr = Bt + (size_t)(n0 + bn) * K + bk;

    for (int k0 = 0; k0 < K; k0 += 32) {
        float4 a0 = ((const float4*)(aptr + k0))[0];
        float4 a1 = ((const float4*)(aptr + k0))[1];
        float4 a2 = ((const float4*)(aptr + k0))[2];
        float4 a3 = ((const float4*)(aptr + k0))[3];
        uint4  b0 = ((const uint4*)(bptr + k0))[0];
        uint4  b1 = ((const uint4*)(bptr + k0))[1];
        __syncthreads();
        unsigned short pk[16];
        float av[16] = {a0.x, a0.y, a0.z, a0.w, a1.x, a1.y, a1.z, a1.w,
                        a2.x, a2.y, a2.z, a2.w, a3.x, a3.y, a3.z, a3.w};
        #pragma unroll
        for (int j = 0; j < 16; j++) pk[j] = f2bf(av[j]);
        *(uint4*)(As + (((ak >> 3)    ) * 128 + am) * 8) = *(uint4*)&pk[0];
        *(uint4*)(As + (((ak >> 3) + 1) * 128 + am) * 8) = *(uint4*)&pk[8];
        *(uint4*)(Bs + (((bk >> 3)    ) * 128 + bn) * 8) = b0;
        *(uint4*)(Bs + (((bk >> 3) + 1) * 128 + bn) * 8) = b1;
        __syncthreads();
        bf16x8 af[4], bfv[4];
        #pragma unroll
        for (int mf = 0; mf < 4; mf++)
            af[mf]  = *(const bf16x8*)(As + (quad * 128 + wm + mf * 16 + l16) * 8);
        #pragma unroll
        for (int nf = 0; nf < 4; nf++)
            bfv[nf] = *(const bf16x8*)(Bs + (quad * 128 + wn + nf * 16 + l16) * 8);
        #pragma unroll
        for (int mf = 0; mf < 4; mf++)
            #pragma unroll
            for (int nf = 0; nf < 4; nf++)
                acc[mf][nf] = __builtin_amdgcn_mfma_f32_16x16x32_bf16(
                                  af[mf], bfv[nf], acc[mf][nf], 0, 0, 0);
    }

    #pragma unroll
    for (int nf = 0; nf < 4; nf++) {
        int col = n0 + wn + nf * 16 + l16;
        float bv = bias ? bias[col] : 0.0f;
        #pragma unroll
        for (int mf = 0; mf < 4; mf++) {
            #pragma unroll
            for (int r = 0; r < 4; r++) {
                int row = m0 + wm + mf * 16 + quad * 4 + r;
                float x = acc[mf][nf][r] + bv;
                if (ACT == 1) x = fmaxf(x, 0.0f);
                else if (ACT == 2) x = tanhf(x);
                else if (ACT == 3) x = 1.0f / (1.0f + expf(-x));
                C[(size_t)row * N + col] = x;
            }
        }
    }
}

// ---------------------------------------------------------------------------
// MFMA fused attention. One block per (b,h), 4 waves.
// Stripes of 16 query rows; content = (q+u)@K^T, pos = (q+v)@kpos^T (full 199,
// gathered via per-wave fp32 LDS scratch), softmax fp32, out = P@V.
// Q and P use hi/lo bf16 split (error-compensated); K/V/kpos single bf16.
#define KP_STRIDE 72    // bf16 row stride for K_s / kpos_s (64+8)
#define PV_STRIDE 136   // bf16 row stride for V_t / P stripes (128+8)
#define POS_STRIDE 210  // fp32 scratch stride (per-wave)
__global__ __launch_bounds__(256) void attn_mfma_kernel(
        const float* __restrict__ q, const float* __restrict__ kv,
        const float* __restrict__ kpos, const float* __restrict__ u,
        const float* __restrict__ v, const int* __restrict__ len_,
        float* __restrict__ out) {
    int b = blockIdx.x >> 3, h = blockIdx.x & 7;
    __shared__ __align__(16) unsigned short K_s[112 * KP_STRIDE];   // 16.1 KB
    __shared__ __align__(16) unsigned short Kp_s[208 * KP_STRIDE];  // 30.0 KB
    __shared__ __align__(16) unsigned short V_t[64 * PV_STRIDE];    // 17.4 KB
    __shared__ __align__(16) char wscratch[4][16 * POS_STRIDE * 4]; // 53.8 KB

    int t = threadIdx.x, wave = t >> 6, lane = t & 63;
    int quad = lane >> 4, l16 = lane & 15;

    // ---- stage K, V (transposed), kpos head-slice as bf16 ----
    for (int idx = t; idx < 128 * 64; idx += 256) {
        int j = idx >> 6, d = idx & 63;
        float kvv = 0.f, vvv = 0.f;
        if (j < 100) {
            const float* p_ = kv + (((size_t)(b * SS + j)) * HH + h) * 128 + d;
            kvv = p_[0]; vvv = p_[64];
        }
        if (j < 112) K_s[j * KP_STRIDE + d] = f2bf(kvv);
        V_t[d * PV_STRIDE + j] = f2bf(vvv);
    }
    for (int idx = t; idx < 208 * 64; idx += 256) {
        int r = idx >> 6, d = idx & 63;
        float pv_ = (r < RR) ? kpos[(size_t)r * DD + h * 64 + d] : 0.f;
        Kp_s[r * KP_STRIDE + d] = f2bf(pv_);
    }
    int len = len_[b];
    // u,v fragments (stripe-invariant)
    float ua[2][8], va[2][8];
    #pragma unroll
    for (int kf = 0; kf < 2; kf++) {
        #pragma unroll
        for (int i = 0; i < 8; i++) {
            ua[kf][i] = u[h * 64 + kf * 32 + quad * 8 + i];
            va[kf][i] = v[h * 64 + kf * 32 + quad * 8 + i];
        }
    }
    float* pos_sc = (float*)wscratch[wave];
    unsigned short* p_hi = (unsigned short*)wscratch[wave];
    unsigned short* p_lo = p_hi + 16 * PV_STRIDE;
    __syncthreads();

    for (int s = wave; s < 7; s += 4) {
        // ---- Q fragments (from global, hi/lo split) ----
        int iq = s * 16 + l16; if (iq > 99) iq = 99;
        const float* qrow = q + ((size_t)(b * SS + iq)) * DD + h * 64;
        bf16x8 qu_h[2], qu_l[2], qv_h[2], qv_l[2];
        #pragma unroll
        for (int kf = 0; kf < 2; kf++) {
            float4 q0 = *(const float4*)(qrow + kf * 32 + quad * 8);
            float4 q1 = *(const float4*)(qrow + kf * 32 + quad * 8 + 4);
            float qa[8] = {q0.x, q0.y, q0.z, q0.w, q1.x, q1.y, q1.z, q1.w};
            float xu[8], xv[8];
            #pragma unroll
            for (int i = 0; i < 8; i++) { xu[i] = qa[i] + ua[kf][i]; xv[i] = qa[i] + va[kf][i]; }
            split8(xu, qu_h[kf], qu_l[kf]);
            split8(xv, qv_h[kf], qv_l[kf]);
        }
        // ---- content scores ----
        floatx4 cacc[7];
        #pragma unroll
        for (int nt = 0; nt < 7; nt++) cacc[nt] = (floatx4){0.f, 0.f, 0.f, 0.f};
        #pragma unroll
        for (int nt = 0; nt < 7; nt++) {
            #pragma unroll
            for (int kf = 0; kf < 2; kf++) {
                bf16x8 kb = *(const bf16x8*)(K_s + (nt * 16 + l16) * KP_STRIDE + kf * 32 + quad * 8);
                cacc[nt] = __builtin_amdgcn_mfma_f32_16x16x32_bf16(qu_h[kf], kb, cacc[nt], 0, 0, 0);
                cacc[nt] = __builtin_amdgcn_mfma_f32_16x16x32_bf16(qu_l[kf], kb, cacc[nt], 0, 0, 0);
            }
        }
        // ---- pos scores (full 199) ----
        {
            floatx4 pacc[13];
            #pragma unroll
            for (int nt = 0; nt < 13; nt++) pacc[nt] = (floatx4){0.f, 0.f, 0.f, 0.f};
            #pragma unroll
            for (int nt = 0; nt < 13; nt++) {
                #pragma unroll
                for (int kf = 0; kf < 2; kf++) {
                    bf16x8 pb = *(const bf16x8*)(Kp_s + (nt * 16 + l16) * KP_STRIDE + kf * 32 + quad * 8);
                    pacc[nt] = __builtin_amdgcn_mfma_f32_16x16x32_bf16(qv_h[kf], pb, pacc[nt], 0, 0, 0);
                    pacc[nt] = __builtin_amdgcn_mfma_f32_16x16x32_bf16(qv_l[kf], pb, pacc[nt], 0, 0, 0);
                }
            }
            #pragma unroll
            for (int nt = 0; nt < 13; nt++)
                #pragma unroll
                for (int r = 0; r < 4; r++)
                    pos_sc[(quad * 4 + r) * POS_STRIDE + nt * 16 + l16] = pacc[nt][r];
        }
        // ---- assemble scores (gather rel-shifted pos), softmax ----
        float sc[7][4];
        #pragma unroll
        for (int nt = 0; nt < 7; nt++) {
            #pragma unroll
            for (int r = 0; r < 4; r++) {
                int irow = s * 16 + quad * 4 + r;
                int j = nt * 16 + l16;
                int ridx = 99 - irow + j;
                ridx = ridx < 0 ? 0 : (ridx > 207 ? 207 : ridx);
                float val = (cacc[nt][r] + pos_sc[(quad * 4 + r) * POS_STRIDE + ridx]) * SCALE_;
                sc[nt][r] = (j < len) ? val : -1e9f;
            }
        }
        float inv[4];
        #pragma unroll
        for (int r = 0; r < 4; r++) {
            float m_ = sc[0][r];
            #pragma unroll
            for (int nt = 1; nt < 7; nt++) m_ = fmaxf(m_, sc[nt][r]);
            #pragma unroll
            for (int o = 8; o; o >>= 1) m_ = fmaxf(m_, __shfl_xor(m_, o));
            float s_ = 0.f;
            #pragma unroll
            for (int nt = 0; nt < 7; nt++) { sc[nt][r] = expf(sc[nt][r] - m_); s_ += sc[nt][r]; }
            #pragma unroll
            for (int o = 8; o; o >>= 1) s_ += __shfl_xor(s_, o);
            inv[r] = 1.0f / s_;
        }
        // ---- write P hi/lo to wave-private LDS ----
        #pragma unroll
        for (int r = 0; r < 4; r++) {
            int row = quad * 4 + r;
            #pragma unroll
            for (int nt = 0; nt < 7; nt++) {
                float p = sc[nt][r] * inv[r];
                unsigned short ph = f2bf(p);
                p_hi[row * PV_STRIDE + nt * 16 + l16] = ph;
                p_lo[row * PV_STRIDE + nt * 16 + l16] = f2bf(p - bf2f(ph));
            }
            p_hi[row * PV_STRIDE + 112 + l16] = 0;
            p_lo[row * PV_STRIDE + 112 + l16] = 0;
        }
        // ---- O = P @ V ----
        bf16x8 pa_h[4], pa_l[4];
        #pragma unroll
        for (int kf = 0; kf < 4; kf++) {
            pa_h[kf] = *(const bf16x8*)(p_hi + l16 * PV_STRIDE + kf * 32 + quad * 8);
            pa_l[kf] = *(const bf16x8*)(p_lo + l16 * PV_STRIDE + kf * 32 + quad * 8);
        }
        floatx4 oacc[4];
        #pragma unroll
        for (int ntd = 0; ntd < 4; ntd++) oacc[ntd] = (floatx4){0.f, 0.f, 0.f, 0.f};
        #pragma unroll
        for (int ntd = 0; ntd < 4; ntd++) {
            #pragma unroll
            for (int kf = 0; kf < 4; kf++) {
                bf16x8 bv = *(const bf16x8*)(V_t + (ntd * 16 + l16) * PV_STRIDE + kf * 32 + quad * 8);
                oacc[ntd] = __builtin_amdgcn_mfma_f32_16x16x32_bf16(pa_h[kf], bv, oacc[ntd], 0, 0, 0);
                oacc[ntd] = __builtin_amdgcn_mfma_f32_16x16x32_bf16(pa_l[kf], bv, oacc[ntd], 0, 0, 0);
            }
        }
        #pragma unroll
        for (int ntd = 0; ntd < 4; ntd++) {
            #pragma unroll
            for (int r = 0; r < 4; r++) {
                int irow = s * 16 + quad * 4 + r;
                if (irow < 100)
                    out[((size_t)(b * SS + irow)) * DD + h * 64 + ntd * 16 + l16] = oacc[ntd][r];
            }
        }
    }
}

// ---------------------------------------------------------------------------
// net = LayerNorm(src + a) * g + b
__global__ void ln_kernel(const float* __restrict__ x, const float* __restrict__ a,
                          const float* __restrict__ g, const float* __restrict__ bb,
                          float* __restrict__ out) {
    int r = blockIdx.x;
    int t = threadIdx.x;
    float4 xv = *(const float4*)(x + (size_t)r * DD + t * 4);
    float4 av = *(const float4*)(a + (size_t)r * DD + t * 4);
    float v0 = xv.x + av.x, v1 = xv.y + av.y, v2 = xv.z + av.z, v3 = xv.w + av.w;
    float sum = v0 + v1 + v2 + v3;
    float sq  = v0 * v0 + v1 * v1 + v2 * v2 + v3 * v3;
    #pragma unroll
    for (int o = 32; o > 0; o >>= 1) {
        sum += __shfl_down(sum, o);
        sq  += __shfl_down(sq, o);
    }
    __shared__ float ls[2], lq[2];
    if ((t & 63) == 0) { ls[t >> 6] = sum; lq[t >> 6] = sq; }
    __syncthreads();
    float S_ = ls[0] + ls[1], Q_ = lq[0] + lq[1];
    float m   = S_ / 512.0f;
    float var = Q_ / 512.0f - m * m;
    float rs  = rsqrtf(var + 1e-5f);
    float4 gv = *(const float4*)(g  + t * 4);
    float4 bv = *(const float4*)(bb + t * 4);
    float4 o4;
    o4.x = (v0 - m) * rs * gv.x + bv.x;
    o4.y = (v1 - m) * rs * gv.y + bv.y;
    o4.z = (v2 - m) * rs * gv.z + bv.z;
    o4.w = (v3 - m) * rs * gv.w + bv.w;
    *(float4*)(out + (size_t)r * DD + t * 4) = o4;
}

// ---------------------------------------------------------------------------
__global__ void combine_kernel(float* __restrict__ src, const float* __restrict__ bg,
                               const float* __restrict__ proj) {
    int idx = blockIdx.x * 256 + threadIdx.x;
    float4 s = ((const float4*)src)[idx];
    float4 g = ((const float4*)bg)[idx];
    float4 p = ((const float4*)proj)[idx];
    s.x = s.x * (1.0f - g.x) + p.x * g.x;
    s.y = s.y * (1.0f - g.y) + p.y * g.y;
    s.z = s.z * (1.0f - g.z) + p.z * g.z;
    s.w = s.w * (1.0f - g.w) + p.w * g.w;
    ((float4*)src)[idx] = s;
}

// ---------------------------------------------------------------------------
extern "C" void kernel_launch(void* const* d_in, const int* in_sizes, int n_in,
                              void* d_out, int out_size, void* d_ws, size_t ws_size,
                              hipStream_t stream) {
    const int*   ids     = (const int*)  d_in[0];
    const int*   src_len = (const int*)  d_in[1];
    const float* emb     = (const float*)d_in[2];
    const float* Wq      = (const float*)d_in[3];
    const float* Wkv     = (const float*)d_in[4];
    const float* Wpos    = (const float*)d_in[5];
    const float* Wout    = (const float*)d_in[6];
    const float* u       = (const float*)d_in[7];
    const float* v       = (const float*)d_in[8];
    const float* ng      = (const float*)d_in[9];
    const float* nb      = (const float*)d_in[10];
    const float* p1_w    = (const float*)d_in[11];
    const float* p1_b    = (const float*)d_in[12];
    const float* p2_w    = (const float*)d_in[13];
    const float* p2_b    = (const float*)d_in[14];
    const float* g1_w    = (const float*)d_in[15];
    const float* g1_b    = (const float*)d_in[16];
    const float* g2_w    = (const float*)d_in[17];
    const float* g2_b    = (const float*)d_in[18];

    float* src = (float*)d_out;

    float* ws   = (float*)d_ws;
    float* kpos = ws;
    float* q    = kpos + (size_t)RR * DD;
    float* kv   = q    + (size_t)MM * DD;
    float* t0   = kv   + (size_t)MM * 2 * DD;
    float* t1   = t0   + (size_t)MM * DD;
    float* ff   = t1   + (size_t)MM * DD;
    unsigned short* wq_t   = (unsigned short*)(ff + (size_t)MM * DFFF);
    unsigned short* wkv_t  = wq_t   + 512 * 512;
    unsigned short* wout_t = wkv_t  + 1024 * 512;
    unsigned short* p1_t   = wout_t + 512 * 512;
    unsigned short* p2_t   = p1_t   + 2048 * 512;
    unsigned short* g1_t   = p2_t   + 512 * 2048;
    unsigned short* g2_t   = g1_t   + 512 * 512;

    hipLaunchKernelGGL(embed_kernel, dim3(MM), dim3(128), 0, stream, ids, emb, src);
    hipLaunchKernelGGL(kpos_kernel, dim3(RR), dim3(DD), 0, stream, Wpos, kpos);
    hipLaunchKernelGGL(wtr_kernel, dim3((512*512 +255)/256), dim3(256), 0, stream, Wq,   wq_t,   512, 512);
    hipLaunchKernelGGL(wtr_kernel, dim3((512*1024+255)/256), dim3(256), 0, stream, Wkv,  wkv_t,  512, 1024);
    hipLaunchKernelGGL(wtr_kernel, dim3((512*512 +255)/256), dim3(256), 0, stream, Wout, wout_t, 512, 512);
    hipLaunchKernelGGL(wtr_kernel, dim3((512*2048+255)/256), dim3(256), 0, stream, p1_w, p1_t,   512, 2048);
    hipLaunchKernelGGL(wtr_kernel, dim3((2048*512+255)/256), dim3(256), 0, stream, p2_w, p2_t,   2048, 512);
    hipLaunchKernelGGL(wtr_kernel, dim3((512*512 +255)/256), dim3(256), 0, stream, g1_w, g1_t,   512, 512);
    hipLaunchKernelGGL(wtr_kernel, dim3((512*512 +255)/256), dim3(256), 0, stream, g2_w, g2_t,   512, 512);

    for (int layer = 0; layer < NLAYERS; layer++) {
        hipLaunchKernelGGL((mgemm_kernel<0>), dim3(512/128,  MM/128), dim3(256), 0, stream,
                           src, wq_t, (const float*)nullptr, q, MM, 512, 512);
        hipLaunchKernelGGL((mgemm_kernel<0>), dim3(1024/128, MM/128), dim3(256), 0, stream,
                           src, wkv_t, (const float*)nullptr, kv, MM, 1024, 512);
        hipLaunchKernelGGL(attn_mfma_kernel, dim3(BB * HH), dim3(256), 0, stream,
                           q, kv, kpos, u, v, src_len, t0);
        hipLaunchKernelGGL((mgemm_kernel<0>), dim3(512/128,  MM/128), dim3(256), 0, stream,
                           t0, wout_t, (const float*)nullptr, t1, MM, 512, 512);
        hipLaunchKernelGGL(ln_kernel, dim3(MM), dim3(128), 0, stream, src, t1, ng, nb, t0);
        hipLaunchKernelGGL((mgemm_kernel<1>), dim3(2048/128, MM/128), dim3(256), 0, stream,
                           t0, p1_t, p1_b, ff, MM, 2048, 512);
        hipLaunchKernelGGL((mgemm_kernel<2>), dim3(512/128,  MM/128), dim3(256), 0, stream,
                           ff, p2_t, p2_b, t1, MM, 512, 2048);
        hipLaunchKernelGGL((mgemm_kernel<1>), dim3(512/128,  MM/128), dim3(256), 0, stream,
                           t0, g1_t, g1_b, q, MM, 512, 512);
        hipLaunchKernelGGL((mgemm_kernel<3>), dim3(512/128,  MM/128), dim3(256), 0, stream,
                           q, g2_t, g2_b, kv, MM, 512, 512);
        hipLaunchKernelGGL(combine_kernel, dim3(MM * DD / 4 / 256), dim3(256), 0, stream,
                           src, kv, t1);
    }
}

// Round 4
// 2307.276 us; speedup vs baseline: 6.0188x; 1.2416x over previous
//
#include <hip/hip_runtime.h>
#include <hip/hip_bf16.h>
#include <math.h>

// Problem constants
#define BB 128
#define SS 100
#define DD 512
#define HH 8
#define DHH 64
#define DFFF 2048
#define RR 199          // 2S-1
#define MM (BB*SS)      // 12800
#define NLAYERS 6
#define SCALE_ 0.125f

typedef __attribute__((ext_vector_type(8))) short bf16x8;
typedef __attribute__((ext_vector_type(4))) float floatx4;
typedef unsigned short ushort_t;

__device__ inline unsigned short f2bf(float f) {
    union { float f; unsigned u; } c; c.f = f;
    unsigned r = c.u + 0x7FFFu + ((c.u >> 16) & 1u);   // RNE
    return (unsigned short)(r >> 16);
}
__device__ inline float bf2f(unsigned short h) {
    union { unsigned u; float f; } c; c.u = ((unsigned)h) << 16;
    return c.f;
}
__device__ inline void split8(const float* x, bf16x8& hi, bf16x8& lo) {
    #pragma unroll
    for (int i = 0; i < 8; i++) {
        unsigned short h_ = f2bf(x[i]);
        hi[i] = (short)h_;
        lo[i] = (short)f2bf(x[i] - bf2f(h_));
    }
}
// async global->LDS, 16 bytes per lane
__device__ inline void gl2lds16(const unsigned short* g, unsigned short* l) {
    __builtin_amdgcn_global_load_lds(
        (const __attribute__((address_space(1))) void*)g,
        (__attribute__((address_space(3))) void*)l, 16, 0, 0);
}

// panel-major offset for bf16 activation/weight matrices: [k/8][ROWS][8]
#define PANEL(buf, rows, r_, k_) ((buf) + ((size_t)((k_) >> 3) * (rows) + (r_)) * 8 + ((k_) & 7))

// ---------------------------------------------------------------------------
// Embedding + sinusoid -> src fp32 AND srcbf panel-major bf16
__global__ void embed_kernel(const int* __restrict__ ids, const float* __restrict__ emb,
                             float* __restrict__ src, unsigned short* __restrict__ srcbf) {
    int r  = blockIdx.x;
    int s  = r % SS;
    int id = ids[r];
    int d0 = threadIdx.x * 4;
    const float c = logf(10000.0f) / 512.0f;
    unsigned short pk[4];
    #pragma unroll
    for (int jj = 0; jj < 4; jj++) {
        int d  = d0 + jj;
        int j2 = d & ~1;
        float freq = expf(-(float)j2 * c);
        float ang  = (float)s * freq;
        float pe   = (d & 1) ? cosf(ang) : sinf(ang);
        float x = emb[id * DD + d] + pe;
        src[r * DD + d] = x;
        pk[jj] = f2bf(x);
    }
    *(uint2*)PANEL(srcbf, MM, r, d0) = *(uint2*)pk;
}

// ---------------------------------------------------------------------------
// k_pos = sinusoid(rel) @ Wpos  -> bf16 flat (199, 512)
__global__ void kpos_kernel(const float* __restrict__ Wpos, unsigned short* __restrict__ kp) {
    int r = blockIdx.x;
    float p = (float)(SS - 1 - r);
    __shared__ float pe[DD];
    int t = threadIdx.x;
    const float c = logf(10000.0f) / 512.0f;
    {
        int j2 = t & ~1;
        float freq = expf(-(float)j2 * c);
        float ang  = p * freq;
        pe[t] = (t & 1) ? cosf(ang) : sinf(ang);
    }
    __syncthreads();
    float acc = 0.0f;
    for (int k = 0; k < DD; k++) acc += pe[k] * Wpos[k * DD + t];
    kp[r * DD + t] = f2bf(acc);
}

// ---------------------------------------------------------------------------
// Weight -> transposed bf16 panel-major: Wt[n][k], panels on k
__global__ void wtr_kernel(const float* __restrict__ W, unsigned short* __restrict__ Wt,
                           int K, int N) {
    int idx = blockIdx.x * 256 + threadIdx.x;
    if (idx >= K * N) return;
    int k = idx / N, n = idx - k * N;
    *PANEL(Wt, N, n, k) = f2bf(W[idx]);
}

// ---------------------------------------------------------------------------
// bf16 MFMA GEMM, m97-style: A panel-major bf16 [K/8][M][8], Bt panel-major
// bf16 [K/8][N][8]. BM=128, BN in {64,128}, BK=32. 256 thr = 4 waves.
// global_load_lds width-16 staging for both tiles.
// ACT: 0 none, 1 relu, 2 tanh, 3 sigmoid.
// CMODE: 0 = fp32 flat, 1 = bf16 panel-major (rows=M), 2 = bf16 flat.
template<int ACT, int CMODE, int BN>
__global__ __launch_bounds__(256) void mgemm(const unsigned short* __restrict__ A,
                                             const unsigned short* __restrict__ Bt,
                                             const float* __restrict__ bias,
                                             float* __restrict__ Cf,
                                             unsigned short* __restrict__ Cb,
                                             int M, int N, int K) {
    __shared__ __align__(16) unsigned short As[4 * 128 * 8];
    __shared__ __align__(16) unsigned short Bs[4 * BN * 8];
    const int NF = BN / 32;
    int t = threadIdx.x, lane = t & 63, wave = t >> 6;
    int quad = lane >> 4, l16 = lane & 15;
    int wm = (wave & 1) * 64, wn = (wave >> 1) * (BN / 2);
    int m0 = blockIdx.y * 128, n0 = blockIdx.x * BN;

    floatx4 acc[4][4];
    #pragma unroll
    for (int i = 0; i < 4; i++)
        #pragma unroll
        for (int j = 0; j < NF; j++) acc[i][j] = (floatx4){0.f, 0.f, 0.f, 0.f};

    for (int k0 = 0; k0 < K; k0 += 32) {
        __syncthreads();   // prior tile reads complete before overwrite
        {   // A panel (wave stages panel #wave): 128 chunks
            const unsigned short* gA = A + ((size_t)((k0 >> 3) + wave) * M + m0) * 8;
            unsigned short* lA = As + wave * 128 * 8;
            gl2lds16(gA + lane * 8,        lA + lane * 8);
            gl2lds16(gA + (64 + lane) * 8, lA + (64 + lane) * 8);
        }
        {   // B panel
            const unsigned short* gB = Bt + ((size_t)((k0 >> 3) + wave) * N + n0) * 8;
            unsigned short* lB = Bs + wave * BN * 8;
            gl2lds16(gB + lane * 8, lB + lane * 8);
            if (BN == 128) gl2lds16(gB + (64 + lane) * 8, lB + (64 + lane) * 8);
        }
        __syncthreads();   // drain: tile ready
        bf16x8 af[4], bfv[4];
        #pragma unroll
        for (int mf = 0; mf < 4; mf++)
            af[mf] = *(const bf16x8*)(As + (quad * 128 + wm + mf * 16 + l16) * 8);
        #pragma unroll
        for (int nf = 0; nf < NF; nf++)
            bfv[nf] = *(const bf16x8*)(Bs + (quad * BN + wn + nf * 16 + l16) * 8);
        #pragma unroll
        for (int mf = 0; mf < 4; mf++)
            #pragma unroll
            for (int nf = 0; nf < NF; nf++)
                acc[mf][nf] = __builtin_amdgcn_mfma_f32_16x16x32_bf16(
                                  af[mf], bfv[nf], acc[mf][nf], 0, 0, 0);
    }

    // epilogue: D col = lane&15, row = quad*4 + reg
    #pragma unroll
    for (int nf = 0; nf < NF; nf++) {
        int col = n0 + wn + nf * 16 + l16;
        float bv = bias ? bias[col] : 0.0f;
        #pragma unroll
        for (int mf = 0; mf < 4; mf++) {
            #pragma unroll
            for (int r = 0; r < 4; r++) {
                int row = m0 + wm + mf * 16 + quad * 4 + r;
                float x = acc[mf][nf][r] + bv;
                if (ACT == 1) x = fmaxf(x, 0.0f);
                else if (ACT == 2) x = tanhf(x);
                else if (ACT == 3) x = 1.0f / (1.0f + expf(-x));
                if (CMODE == 0)      Cf[(size_t)row * N + col] = x;
                else if (CMODE == 1) *PANEL(Cb, M, row, col) = f2bf(x);
                else                 Cb[(size_t)row * N + col] = f2bf(x);
            }
        }
    }
}

// ---------------------------------------------------------------------------
// MFMA fused attention, slimmed: bf16 staging, windowed pos (128 cols, exact),
// bf16 pos scratch, two-pass hi/lo PV. LDS = 79.6 KB -> 2 blocks/CU.
#define KPST 72     // K_s / Kp_s row stride (shorts)
#define VTST 136    // V_t row stride
#define PSST 136    // per-wave scratch row stride
__global__ __launch_bounds__(256) void attn_kernel2(
        const float* __restrict__ q, const unsigned short* __restrict__ kvb,
        const unsigned short* __restrict__ kpbf, const float* __restrict__ u,
        const float* __restrict__ v, const int* __restrict__ len_,
        unsigned short* __restrict__ outp) {
    int b = blockIdx.x >> 3, h = blockIdx.x & 7;
    __shared__ __align__(16) unsigned short K_s[112 * KPST];   // 16.1 KB
    __shared__ __align__(16) unsigned short Kp_s[199 * KPST];  // 28.7 KB
    __shared__ __align__(16) unsigned short V_t[64 * VTST];    // 17.4 KB
    __shared__ __align__(16) unsigned short wsc[4][16 * PSST]; // 17.4 KB

    int t = threadIdx.x, wave = t >> 6, lane = t & 63;
    int quad = lane >> 4, l16 = lane & 15;

    // ---- stage K (vector), kpos (vector), V transposed (scalar) ----
    for (int idx = t; idx < 112 * 16; idx += 256) {
        int j = idx >> 4, d4 = (idx & 15) * 4;
        uint2 kk = make_uint2(0u, 0u);
        if (j < 100)
            kk = *(const uint2*)(kvb + (((size_t)(b * SS + j)) * HH + h) * 128 + d4);
        *(uint2*)(K_s + j * KPST + d4) = kk;
    }
    for (int idx = t; idx < 199 * 16; idx += 256) {
        int r = idx >> 4, d4 = (idx & 15) * 4;
        *(uint2*)(Kp_s + r * KPST + d4) =
            *(const uint2*)(kpbf + (size_t)r * DD + h * 64 + d4);
    }
    for (int idx = t; idx < 128 * 64; idx += 256) {
        int j = idx >> 6, d = idx & 63;
        unsigned short vv = 0;
        if (j < 100) vv = kvb[(((size_t)(b * SS + j)) * HH + h) * 128 + 64 + d];
        V_t[d * VTST + j] = vv;
    }
    int len = len_[b];
    float ua[2][8], va[2][8];
    #pragma unroll
    for (int kf = 0; kf < 2; kf++)
        #pragma unroll
        for (int i = 0; i < 8; i++) {
            ua[kf][i] = u[h * 64 + kf * 32 + quad * 8 + i];
            va[kf][i] = v[h * 64 + kf * 32 + quad * 8 + i];
        }
    unsigned short* psc = wsc[wave];
    __syncthreads();

    for (int s = wave; s < 7; s += 4) {
        // ---- Q fragments (fp32 global, hi/lo split) ----
        int iq = s * 16 + l16; if (iq > 99) iq = 99;
        const float* qrow = q + ((size_t)(b * SS + iq)) * DD + h * 64;
        bf16x8 qu_h[2], qu_l[2], qv_h[2], qv_l[2];
        #pragma unroll
        for (int kf = 0; kf < 2; kf++) {
            float4 q0 = *(const float4*)(qrow + kf * 32 + quad * 8);
            float4 q1 = *(const float4*)(qrow + kf * 32 + quad * 8 + 4);
            float qa[8] = {q0.x, q0.y, q0.z, q0.w, q1.x, q1.y, q1.z, q1.w};
            float xu[8], xv[8];
            #pragma unroll
            for (int i = 0; i < 8; i++) { xu[i] = qa[i] + ua[kf][i]; xv[i] = qa[i] + va[kf][i]; }
            split8(xu, qu_h[kf], qu_l[kf]);
            split8(xv, qv_h[kf], qv_l[kf]);
        }
        // ---- content scores ----
        floatx4 cacc[7];
        #pragma unroll
        for (int nt = 0; nt < 7; nt++) cacc[nt] = (floatx4){0.f, 0.f, 0.f, 0.f};
        #pragma unroll
        for (int nt = 0; nt < 7; nt++)
            #pragma unroll
            for (int kf = 0; kf < 2; kf++) {
                bf16x8 kb = *(const bf16x8*)(K_s + (nt * 16 + l16) * KPST + kf * 32 + quad * 8);
                cacc[nt] = __builtin_amdgcn_mfma_f32_16x16x32_bf16(qu_h[kf], kb, cacc[nt], 0, 0, 0);
                cacc[nt] = __builtin_amdgcn_mfma_f32_16x16x32_bf16(qu_l[kf], kb, cacc[nt], 0, 0, 0);
            }
        // ---- pos scores, 128-wide window [w0, w0+127] (covers stripe range) ----
        int w0 = 84 - 16 * s; w0 = w0 < 0 ? 0 : (w0 > 71 ? 71 : w0);
        {
            floatx4 pacc[8];
            #pragma unroll
            for (int nt = 0; nt < 8; nt++) pacc[nt] = (floatx4){0.f, 0.f, 0.f, 0.f};
            #pragma unroll
            for (int nt = 0; nt < 8; nt++)
                #pragma unroll
                for (int kf = 0; kf < 2; kf++) {
                    bf16x8 pb = *(const bf16x8*)(Kp_s + (w0 + nt * 16 + l16) * KPST + kf * 32 + quad * 8);
                    pacc[nt] = __builtin_amdgcn_mfma_f32_16x16x32_bf16(qv_h[kf], pb, pacc[nt], 0, 0, 0);
                    pacc[nt] = __builtin_amdgcn_mfma_f32_16x16x32_bf16(qv_l[kf], pb, pacc[nt], 0, 0, 0);
                }
            #pragma unroll
            for (int nt = 0; nt < 8; nt++)
                #pragma unroll
                for (int r = 0; r < 4; r++)
                    psc[(quad * 4 + r) * PSST + nt * 16 + l16] = f2bf(pacc[nt][r]);
        }
        // ---- assemble + softmax (fp32) ----
        float sc[7][4];
        #pragma unroll
        for (int nt = 0; nt < 7; nt++)
            #pragma unroll
            for (int r = 0; r < 4; r++) {
                int irow = s * 16 + quad * 4 + r;
                int j = nt * 16 + l16;
                int ro = 99 - irow + j - w0;
                ro = ro < 0 ? 0 : (ro > 135 ? 135 : ro);
                float val = (cacc[nt][r] + bf2f(psc[(quad * 4 + r) * PSST + ro])) * SCALE_;
                sc[nt][r] = (j < len) ? val : -1e9f;
            }
        float inv[4];
        #pragma unroll
        for (int r = 0; r < 4; r++) {
            float m_ = sc[0][r];
            #pragma unroll
            for (int nt = 1; nt < 7; nt++) m_ = fmaxf(m_, sc[nt][r]);
            #pragma unroll
            for (int o = 8; o; o >>= 1) m_ = fmaxf(m_, __shfl_xor(m_, o));
            float s_ = 0.f;
            #pragma unroll
            for (int nt = 0; nt < 7; nt++) { sc[nt][r] = expf(sc[nt][r] - m_); s_ += sc[nt][r]; }
            #pragma unroll
            for (int o = 8; o; o >>= 1) s_ += __shfl_xor(s_, o);
            inv[r] = 1.0f / s_;
        }
        // ---- PV in two passes (hi then lo) over one wave-private buffer ----
        floatx4 oacc[4];
        #pragma unroll
        for (int ntd = 0; ntd < 4; ntd++) oacc[ntd] = (floatx4){0.f, 0.f, 0.f, 0.f};
        #pragma unroll
        for (int pass = 0; pass < 2; pass++) {
            #pragma unroll
            for (int r = 0; r < 4; r++) {
                int row = quad * 4 + r;
                #pragma unroll
                for (int nt = 0; nt < 7; nt++) {
                    float pv = sc[nt][r] * inv[r];
                    unsigned short ph = f2bf(pv);
                    psc[row * PSST + nt * 16 + l16] =
                        (pass == 0) ? ph : f2bf(pv - bf2f(ph));
                }
                psc[row * PSST + 112 + l16] = 0;
            }
            bf16x8 pa[4];
            #pragma unroll
            for (int kf = 0; kf < 4; kf++)
                pa[kf] = *(const bf16x8*)(psc + l16 * PSST + kf * 32 + quad * 8);
            #pragma unroll
            for (int ntd = 0; ntd < 4; ntd++)
                #pragma unroll
                for (int kf = 0; kf < 4; kf++) {
                    bf16x8 bv = *(const bf16x8*)(V_t + (ntd * 16 + l16) * VTST + kf * 32 + quad * 8);
                    oacc[ntd] = __builtin_amdgcn_mfma_f32_16x16x32_bf16(pa[kf], bv, oacc[ntd], 0, 0, 0);
                }
        }
        // ---- write attn-out as bf16 panel-major (feeds Wout GEMM) ----
        #pragma unroll
        for (int ntd = 0; ntd < 4; ntd++)
            #pragma unroll
            for (int r = 0; r < 4; r++) {
                int irow = s * 16 + quad * 4 + r;
                if (irow < 100) {
                    int col = h * 64 + ntd * 16 + l16;
                    int row = b * SS + irow;
                    *PANEL(outp, MM, row, col) = f2bf(oacc[ntd][r]);
                }
            }
    }
}

// ---------------------------------------------------------------------------
// net = LayerNorm(src + a) -> bf16 panel-major (only feeds GEMMs)
__global__ void ln_kernel(const float* __restrict__ x, const float* __restrict__ a,
                          const float* __restrict__ g, const float* __restrict__ bb,
                          unsigned short* __restrict__ outp) {
    int r = blockIdx.x;
    int t = threadIdx.x;
    float4 xv = *(const float4*)(x + (size_t)r * DD + t * 4);
    float4 av = *(const float4*)(a + (size_t)r * DD + t * 4);
    float v0 = xv.x + av.x, v1 = xv.y + av.y, v2 = xv.z + av.z, v3 = xv.w + av.w;
    float sum = v0 + v1 + v2 + v3;
    float sq  = v0 * v0 + v1 * v1 + v2 * v2 + v3 * v3;
    #pragma unroll
    for (int o = 32; o > 0; o >>= 1) {
        sum += __shfl_down(sum, o);
        sq  += __shfl_down(sq, o);
    }
    __shared__ float ls[2], lq[2];
    if ((t & 63) == 0) { ls[t >> 6] = sum; lq[t >> 6] = sq; }
    __syncthreads();
    float S_ = ls[0] + ls[1], Q_ = lq[0] + lq[1];
    float m   = S_ / 512.0f;
    float var = Q_ / 512.0f - m * m;
    float rs  = rsqrtf(var + 1e-5f);
    float4 gv = *(const float4*)(g  + t * 4);
    float4 bv = *(const float4*)(bb + t * 4);
    unsigned short pk[4];
    pk[0] = f2bf((v0 - m) * rs * gv.x + bv.x);
    pk[1] = f2bf((v1 - m) * rs * gv.y + bv.y);
    pk[2] = f2bf((v2 - m) * rs * gv.z + bv.z);
    pk[3] = f2bf((v3 - m) * rs * gv.w + bv.w);
    *(uint2*)PANEL(outp, MM, r, t * 4) = *(uint2*)pk;
}

// ---------------------------------------------------------------------------
// src = src*(1-bg) + proj*bg; also emit bf16 panel copy for next layer's GEMMs
__global__ void combine_kernel(float* __restrict__ src, const float* __restrict__ bg,
                               const float* __restrict__ proj,
                               unsigned short* __restrict__ srcbf) {
    int r = blockIdx.x, t = threadIdx.x;
    size_t off = (size_t)r * DD + t * 4;
    float4 s = *(const float4*)(src + off);
    float4 g = *(const float4*)(bg + off);
    float4 p = *(const float4*)(proj + off);
    s.x = s.x * (1.0f - g.x) + p.x * g.x;
    s.y = s.y * (1.0f - g.y) + p.y * g.y;
    s.z = s.z * (1.0f - g.z) + p.z * g.z;
    s.w = s.w * (1.0f - g.w) + p.w * g.w;
    *(float4*)(src + off) = s;
    unsigned short pk[4] = {f2bf(s.x), f2bf(s.y), f2bf(s.z), f2bf(s.w)};
    *(uint2*)PANEL(srcbf, MM, r, t * 4) = *(uint2*)pk;
}

// ---------------------------------------------------------------------------
extern "C" void kernel_launch(void* const* d_in, const int* in_sizes, int n_in,
                              void* d_out, int out_size, void* d_ws, size_t ws_size,
                              hipStream_t stream) {
    const int*   ids     = (const int*)  d_in[0];
    const int*   src_len = (const int*)  d_in[1];
    const float* emb     = (const float*)d_in[2];
    const float* Wq      = (const float*)d_in[3];
    const float* Wkv     = (const float*)d_in[4];
    const float* Wpos    = (const float*)d_in[5];
    const float* Wout    = (const float*)d_in[6];
    const float* u       = (const float*)d_in[7];
    const float* v       = (const float*)d_in[8];
    const float* ng      = (const float*)d_in[9];
    const float* nb      = (const float*)d_in[10];
    const float* p1_w    = (const float*)d_in[11];
    const float* p1_b    = (const float*)d_in[12];
    const float* p2_w    = (const float*)d_in[13];
    const float* p2_b    = (const float*)d_in[14];
    const float* g1_w    = (const float*)d_in[15];
    const float* g1_b    = (const float*)d_in[16];
    const float* g2_w    = (const float*)d_in[17];
    const float* g2_b    = (const float*)d_in[18];

    float* src = (float*)d_out;

    // workspace layout
    float* ws     = (float*)d_ws;
    float* q      = ws;                              // M*512 f
    float* t1     = q    + (size_t)MM * DD;          // M*512 f
    float* proj   = t1   + (size_t)MM * DD;          // M*512 f
    float* bg     = proj + (size_t)MM * DD;          // M*512 f
    unsigned short* kpbf  = (unsigned short*)(bg + (size_t)MM * DD); // RR*512
    unsigned short* srcbf = kpbf  + (size_t)RR * DD;   // M*512 panel
    unsigned short* netbf = srcbf + (size_t)MM * DD;   // M*512 panel
    unsigned short* t0p   = netbf + (size_t)MM * DD;   // M*512 panel (attn out)
    unsigned short* kvb   = t0p   + (size_t)MM * DD;   // M*1024 flat
    unsigned short* ffb   = kvb   + (size_t)MM * 2 * DD; // M*2048 panel
    unsigned short* hgb   = ffb   + (size_t)MM * DFFF;   // M*512 panel
    unsigned short* wq_t   = hgb   + (size_t)MM * DD;
    unsigned short* wkv_t  = wq_t   + 512 * 512;
    unsigned short* wout_t = wkv_t  + 1024 * 512;
    unsigned short* p1_t   = wout_t + 512 * 512;
    unsigned short* p2_t   = p1_t   + 2048 * 512;
    unsigned short* g1_t   = p2_t   + 512 * 2048;
    unsigned short* g2_t   = g1_t   + 512 * 512;

    // one-time prep
    embed_kernel<<<MM, 128, 0, stream>>>(ids, emb, src, srcbf);
    kpos_kernel<<<RR, DD, 0, stream>>>(Wpos, kpbf);
    wtr_kernel<<<(512*512 +255)/256, 256, 0, stream>>>(Wq,   wq_t,   512, 512);
    wtr_kernel<<<(512*1024+255)/256, 256, 0, stream>>>(Wkv,  wkv_t,  512, 1024);
    wtr_kernel<<<(512*512 +255)/256, 256, 0, stream>>>(Wout, wout_t, 512, 512);
    wtr_kernel<<<(512*2048+255)/256, 256, 0, stream>>>(p1_w, p1_t,   512, 2048);
    wtr_kernel<<<(2048*512+255)/256, 256, 0, stream>>>(p2_w, p2_t,   2048, 512);
    wtr_kernel<<<(512*512 +255)/256, 256, 0, stream>>>(g1_w, g1_t,   512, 512);
    wtr_kernel<<<(512*512 +255)/256, 256, 0, stream>>>(g2_w, g2_t,   512, 512);

    for (int layer = 0; layer < NLAYERS; layer++) {
        // q = src @ Wq (fp32 out)
        mgemm<0,0,64><<<dim3(8, 100), 256, 0, stream>>>(
            srcbf, wq_t, (const float*)nullptr, q, (unsigned short*)nullptr, MM, 512, 512);
        // kv = src @ Wkv (bf16 flat out)
        mgemm<0,2,128><<<dim3(8, 100), 256, 0, stream>>>(
            srcbf, wkv_t, (const float*)nullptr, (float*)nullptr, kvb, MM, 1024, 512);
        // fused attention -> t0p (bf16 panel)
        attn_kernel2<<<BB * HH, 256, 0, stream>>>(q, kvb, kpbf, u, v, src_len, t0p);
        // a = attn_out @ Wout (fp32 out)
        mgemm<0,0,64><<<dim3(8, 100), 256, 0, stream>>>(
            t0p, wout_t, (const float*)nullptr, t1, (unsigned short*)nullptr, MM, 512, 512);
        // net = LN(src + a) -> netbf (bf16 panel)
        ln_kernel<<<MM, 128, 0, stream>>>(src, t1, ng, nb, netbf);
        // h1 = relu(net @ p1_w + b) -> ffb (bf16 panel)
        mgemm<1,1,128><<<dim3(16, 100), 256, 0, stream>>>(
            netbf, p1_t, p1_b, (float*)nullptr, ffb, MM, 2048, 512);
        // proj = tanh(h1 @ p2_w + b) (fp32 out)
        mgemm<2,0,64><<<dim3(8, 100), 256, 0, stream>>>(
            ffb, p2_t, p2_b, proj, (unsigned short*)nullptr, MM, 512, 2048);
        // hg = relu(net @ g1_w + b) -> hgb (bf16 panel)
        mgemm<1,1,64><<<dim3(8, 100), 256, 0, stream>>>(
            netbf, g1_t, g1_b, (float*)nullptr, hgb, MM, 512, 512);
        // bgate = sigmoid(hg @ g2_w + b) (fp32 out)
        mgemm<3,0,64><<<dim3(8, 100), 256, 0, stream>>>(
            hgb, g2_t, g2_b, bg, (unsigned short*)nullptr, MM, 512, 512);
        // src = src*(1-bg) + proj*bg (+ bf16 panel copy)
        combine_kernel<<<MM, 128, 0, stream>>>(src, bg, proj, srcbf);
    }
}

// Round 5
// 2001.423 us; speedup vs baseline: 6.9385x; 1.1528x over previous
//
#include <hip/hip_runtime.h>
#include <hip/hip_bf16.h>
#include <math.h>

// Problem constants
#define BB 128
#define SS 100
#define DD 512
#define HH 8
#define DHH 64
#define DFFF 2048
#define RR 199          // 2S-1
#define MM (BB*SS)      // 12800
#define NLAYERS 6
#define SCALE_ 0.125f

typedef __attribute__((ext_vector_type(8))) short bf16x8;
typedef __attribute__((ext_vector_type(4))) float floatx4;

__device__ inline unsigned short f2bf(float f) {
    union { float f; unsigned u; } c; c.f = f;
    unsigned r = c.u + 0x7FFFu + ((c.u >> 16) & 1u);   // RNE
    return (unsigned short)(r >> 16);
}
__device__ inline float bf2f(unsigned short h) {
    union { unsigned u; float f; } c; c.u = ((unsigned)h) << 16;
    return c.f;
}
__device__ inline void split8(const float* x, bf16x8& hi, bf16x8& lo) {
    #pragma unroll
    for (int i = 0; i < 8; i++) {
        unsigned short h_ = f2bf(x[i]);
        hi[i] = (short)h_;
        lo[i] = (short)f2bf(x[i] - bf2f(h_));
    }
}
// async global->LDS, 16 bytes per lane
__device__ inline void gl2lds16(const unsigned short* g, unsigned short* l) {
    __builtin_amdgcn_global_load_lds(
        (const __attribute__((address_space(1))) void*)g,
        (__attribute__((address_space(3))) void*)l, 16, 0, 0);
}

// panel-major offset for bf16 matrices: [k/8][ROWS][8]
#define PANEL(buf, rows, r_, k_) ((buf) + ((size_t)((k_) >> 3) * (rows) + (r_)) * 8 + ((k_) & 7))

// ---------------------------------------------------------------------------
__global__ void embed_kernel(const int* __restrict__ ids, const float* __restrict__ emb,
                             float* __restrict__ src, unsigned short* __restrict__ srcbf) {
    int r  = blockIdx.x;
    int s  = r % SS;
    int id = ids[r];
    int d0 = threadIdx.x * 4;
    const float c = logf(10000.0f) / 512.0f;
    unsigned short pk[4];
    #pragma unroll
    for (int jj = 0; jj < 4; jj++) {
        int d  = d0 + jj;
        int j2 = d & ~1;
        float freq = expf(-(float)j2 * c);
        float ang  = (float)s * freq;
        float pe   = (d & 1) ? cosf(ang) : sinf(ang);
        float x = emb[id * DD + d] + pe;
        src[r * DD + d] = x;
        pk[jj] = f2bf(x);
    }
    *(uint2*)PANEL(srcbf, MM, r, d0) = *(uint2*)pk;
}

// ---------------------------------------------------------------------------
__global__ void kpos_kernel(const float* __restrict__ Wpos, unsigned short* __restrict__ kp) {
    int r = blockIdx.x;
    float p = (float)(SS - 1 - r);
    __shared__ float pe[DD];
    int t = threadIdx.x;
    const float c = logf(10000.0f) / 512.0f;
    {
        int j2 = t & ~1;
        float freq = expf(-(float)j2 * c);
        float ang  = p * freq;
        pe[t] = (t & 1) ? cosf(ang) : sinf(ang);
    }
    __syncthreads();
    float acc = 0.0f;
    for (int k = 0; k < DD; k++) acc += pe[k] * Wpos[k * DD + t];
    kp[r * DD + t] = f2bf(acc);
}

// ---------------------------------------------------------------------------
__global__ void wtr_kernel(const float* __restrict__ W, unsigned short* __restrict__ Wt,
                           int K, int N) {
    int idx = blockIdx.x * 256 + threadIdx.x;
    if (idx >= K * N) return;
    int k = idx / N, n = idx - k * N;
    *PANEL(Wt, N, n, k) = f2bf(W[idx]);
}

// ---------------------------------------------------------------------------
// bf16 MFMA GEMM with XCD-chunked swizzle.
// A panel-major bf16 [K/8][M][8], Bt panel-major bf16 [K/8][N][8].
// BM=128, BN in {64,128}, BK=32. 256 thr = 4 waves, global_load_lds staging.
// Swizzle: bid%8 = XCD; each XCD owns a contiguous chunk of m-tiles for ALL
// n-tiles (m fastest) so its private L2 streams the A chunk once.
// ACT: 0 none, 1 relu, 2 tanh, 3 sigmoid.
// CMODE: 0 = fp32 flat, 1 = bf16 panel-major (rows=M), 2 = bf16 flat.
template<int ACT, int CMODE, int BN>
__global__ __launch_bounds__(256) void mgemm(const unsigned short* __restrict__ A,
                                             const unsigned short* __restrict__ Bt,
                                             const float* __restrict__ bias,
                                             float* __restrict__ Cf,
                                             unsigned short* __restrict__ Cb,
                                             int M, int N, int K) {
    const int NF = BN / 32;
    int nm = M >> 7, nn = N / BN;
    int bid = blockIdx.x;
    int xcd = bid & 7, slot = bid >> 3;
    int c0 = (xcd * nm) >> 3, c1 = ((xcd + 1) * nm) >> 3;
    int cm = c1 - c0;
    if (slot >= cm * nn) return;
    int m0 = (c0 + (slot % cm)) * 128;
    int n0 = (slot / cm) * BN;

    __shared__ __align__(16) unsigned short As[4 * 128 * 8];
    __shared__ __align__(16) unsigned short Bs[4 * BN * 8];
    int t = threadIdx.x, lane = t & 63, wave = t >> 6;
    int quad = lane >> 4, l16 = lane & 15;
    int wm = (wave & 1) * 64, wn = (wave >> 1) * (BN / 2);

    floatx4 acc[4][4];
    #pragma unroll
    for (int i = 0; i < 4; i++)
        #pragma unroll
        for (int j = 0; j < NF; j++) acc[i][j] = (floatx4){0.f, 0.f, 0.f, 0.f};

    for (int k0 = 0; k0 < K; k0 += 32) {
        __syncthreads();
        {   // A panel (wave stages panel #wave)
            const unsigned short* gA = A + ((size_t)((k0 >> 3) + wave) * M + m0) * 8;
            unsigned short* lA = As + wave * 128 * 8;
            gl2lds16(gA + lane * 8,        lA + lane * 8);
            gl2lds16(gA + (64 + lane) * 8, lA + (64 + lane) * 8);
        }
        {   // B panel
            const unsigned short* gB = Bt + ((size_t)((k0 >> 3) + wave) * N + n0) * 8;
            unsigned short* lB = Bs + wave * BN * 8;
            gl2lds16(gB + lane * 8, lB + lane * 8);
            if (BN == 128) gl2lds16(gB + (64 + lane) * 8, lB + (64 + lane) * 8);
        }
        __syncthreads();
        bf16x8 af[4], bfv[4];
        #pragma unroll
        for (int mf = 0; mf < 4; mf++)
            af[mf] = *(const bf16x8*)(As + (quad * 128 + wm + mf * 16 + l16) * 8);
        #pragma unroll
        for (int nf = 0; nf < NF; nf++)
            bfv[nf] = *(const bf16x8*)(Bs + (quad * BN + wn + nf * 16 + l16) * 8);
        #pragma unroll
        for (int mf = 0; mf < 4; mf++)
            #pragma unroll
            for (int nf = 0; nf < NF; nf++)
                acc[mf][nf] = __builtin_amdgcn_mfma_f32_16x16x32_bf16(
                                  af[mf], bfv[nf], acc[mf][nf], 0, 0, 0);
    }

    #pragma unroll
    for (int nf = 0; nf < NF; nf++) {
        int col = n0 + wn + nf * 16 + l16;
        float bv = bias ? bias[col] : 0.0f;
        #pragma unroll
        for (int mf = 0; mf < 4; mf++) {
            #pragma unroll
            for (int r = 0; r < 4; r++) {
                int row = m0 + wm + mf * 16 + quad * 4 + r;
                float x = acc[mf][nf][r] + bv;
                if (ACT == 1) x = fmaxf(x, 0.0f);
                else if (ACT == 2) x = tanhf(x);
                else if (ACT == 3) x = 1.0f / (1.0f + expf(-x));
                if (CMODE == 0)      Cf[(size_t)row * N + col] = x;
                else if (CMODE == 1) *PANEL(Cb, M, row, col) = f2bf(x);
                else                 Cb[(size_t)row * N + col] = f2bf(x);
            }
        }
    }
}
// host-side grid size for the swizzled mgemm
static inline int mgemm_grid(int M, int N, int BN) {
    int nm = M >> 7, nn = N / BN;
    int cmmax = 0;
    for (int x = 0; x < 8; x++) {
        int c = ((x + 1) * nm) / 8 - (x * nm) / 8;
        if (c > cmmax) cmmax = c;
    }
    return 8 * cmmax * nn;
}

// ---------------------------------------------------------------------------
// MFMA fused attention (unchanged from round 4)
#define KPST 72
#define VTST 136
#define PSST 136
__global__ __launch_bounds__(256) void attn_kernel2(
        const float* __restrict__ q, const unsigned short* __restrict__ kvb,
        const unsigned short* __restrict__ kpbf, const float* __restrict__ u,
        const float* __restrict__ v, const int* __restrict__ len_,
        unsigned short* __restrict__ outp) {
    int b = blockIdx.x >> 3, h = blockIdx.x & 7;
    __shared__ __align__(16) unsigned short K_s[112 * KPST];
    __shared__ __align__(16) unsigned short Kp_s[199 * KPST];
    __shared__ __align__(16) unsigned short V_t[64 * VTST];
    __shared__ __align__(16) unsigned short wsc[4][16 * PSST];

    int t = threadIdx.x, wave = t >> 6, lane = t & 63;
    int quad = lane >> 4, l16 = lane & 15;

    for (int idx = t; idx < 112 * 16; idx += 256) {
        int j = idx >> 4, d4 = (idx & 15) * 4;
        uint2 kk = make_uint2(0u, 0u);
        if (j < 100)
            kk = *(const uint2*)(kvb + (((size_t)(b * SS + j)) * HH + h) * 128 + d4);
        *(uint2*)(K_s + j * KPST + d4) = kk;
    }
    for (int idx = t; idx < 199 * 16; idx += 256) {
        int r = idx >> 4, d4 = (idx & 15) * 4;
        *(uint2*)(Kp_s + r * KPST + d4) =
            *(const uint2*)(kpbf + (size_t)r * DD + h * 64 + d4);
    }
    for (int idx = t; idx < 128 * 64; idx += 256) {
        int j = idx >> 6, d = idx & 63;
        unsigned short vv = 0;
        if (j < 100) vv = kvb[(((size_t)(b * SS + j)) * HH + h) * 128 + 64 + d];
        V_t[d * VTST + j] = vv;
    }
    int len = len_[b];
    float ua[2][8], va[2][8];
    #pragma unroll
    for (int kf = 0; kf < 2; kf++)
        #pragma unroll
        for (int i = 0; i < 8; i++) {
            ua[kf][i] = u[h * 64 + kf * 32 + quad * 8 + i];
            va[kf][i] = v[h * 64 + kf * 32 + quad * 8 + i];
        }
    unsigned short* psc = wsc[wave];
    __syncthreads();

    for (int s = wave; s < 7; s += 4) {
        int iq = s * 16 + l16; if (iq > 99) iq = 99;
        const float* qrow = q + ((size_t)(b * SS + iq)) * DD + h * 64;
        bf16x8 qu_h[2], qu_l[2], qv_h[2], qv_l[2];
        #pragma unroll
        for (int kf = 0; kf < 2; kf++) {
            float4 q0 = *(const float4*)(qrow + kf * 32 + quad * 8);
            float4 q1 = *(const float4*)(qrow + kf * 32 + quad * 8 + 4);
            float qa[8] = {q0.x, q0.y, q0.z, q0.w, q1.x, q1.y, q1.z, q1.w};
            float xu[8], xv[8];
            #pragma unroll
            for (int i = 0; i < 8; i++) { xu[i] = qa[i] + ua[kf][i]; xv[i] = qa[i] + va[kf][i]; }
            split8(xu, qu_h[kf], qu_l[kf]);
            split8(xv, qv_h[kf], qv_l[kf]);
        }
        floatx4 cacc[7];
        #pragma unroll
        for (int nt = 0; nt < 7; nt++) cacc[nt] = (floatx4){0.f, 0.f, 0.f, 0.f};
        #pragma unroll
        for (int nt = 0; nt < 7; nt++)
            #pragma unroll
            for (int kf = 0; kf < 2; kf++) {
                bf16x8 kb = *(const bf16x8*)(K_s + (nt * 16 + l16) * KPST + kf * 32 + quad * 8);
                cacc[nt] = __builtin_amdgcn_mfma_f32_16x16x32_bf16(qu_h[kf], kb, cacc[nt], 0, 0, 0);
                cacc[nt] = __builtin_amdgcn_mfma_f32_16x16x32_bf16(qu_l[kf], kb, cacc[nt], 0, 0, 0);
            }
        int w0 = 84 - 16 * s; w0 = w0 < 0 ? 0 : (w0 > 71 ? 71 : w0);
        {
            floatx4 pacc[8];
            #pragma unroll
            for (int nt = 0; nt < 8; nt++) pacc[nt] = (floatx4){0.f, 0.f, 0.f, 0.f};
            #pragma unroll
            for (int nt = 0; nt < 8; nt++)
                #pragma unroll
                for (int kf = 0; kf < 2; kf++) {
                    bf16x8 pb = *(const bf16x8*)(Kp_s + (w0 + nt * 16 + l16) * KPST + kf * 32 + quad * 8);
                    pacc[nt] = __builtin_amdgcn_mfma_f32_16x16x32_bf16(qv_h[kf], pb, pacc[nt], 0, 0, 0);
                    pacc[nt] = __builtin_amdgcn_mfma_f32_16x16x32_bf16(qv_l[kf], pb, pacc[nt], 0, 0, 0);
                }
            #pragma unroll
            for (int nt = 0; nt < 8; nt++)
                #pragma unroll
                for (int r = 0; r < 4; r++)
                    psc[(quad * 4 + r) * PSST + nt * 16 + l16] = f2bf(pacc[nt][r]);
        }
        float sc[7][4];
        #pragma unroll
        for (int nt = 0; nt < 7; nt++)
            #pragma unroll
            for (int r = 0; r < 4; r++) {
                int irow = s * 16 + quad * 4 + r;
                int j = nt * 16 + l16;
                int ro = 99 - irow + j - w0;
                ro = ro < 0 ? 0 : (ro > 135 ? 135 : ro);
                float val = (cacc[nt][r] + bf2f(psc[(quad * 4 + r) * PSST + ro])) * SCALE_;
                sc[nt][r] = (j < len) ? val : -1e9f;
            }
        float inv[4];
        #pragma unroll
        for (int r = 0; r < 4; r++) {
            float m_ = sc[0][r];
            #pragma unroll
            for (int nt = 1; nt < 7; nt++) m_ = fmaxf(m_, sc[nt][r]);
            #pragma unroll
            for (int o = 8; o; o >>= 1) m_ = fmaxf(m_, __shfl_xor(m_, o));
            float s_ = 0.f;
            #pragma unroll
            for (int nt = 0; nt < 7; nt++) { sc[nt][r] = expf(sc[nt][r] - m_); s_ += sc[nt][r]; }
            #pragma unroll
            for (int o = 8; o; o >>= 1) s_ += __shfl_xor(s_, o);
            inv[r] = 1.0f / s_;
        }
        floatx4 oacc[4];
        #pragma unroll
        for (int ntd = 0; ntd < 4; ntd++) oacc[ntd] = (floatx4){0.f, 0.f, 0.f, 0.f};
        #pragma unroll
        for (int pass = 0; pass < 2; pass++) {
            #pragma unroll
            for (int r = 0; r < 4; r++) {
                int row = quad * 4 + r;
                #pragma unroll
                for (int nt = 0; nt < 7; nt++) {
                    float pv = sc[nt][r] * inv[r];
                    unsigned short ph = f2bf(pv);
                    psc[row * PSST + nt * 16 + l16] =
                        (pass == 0) ? ph : f2bf(pv - bf2f(ph));
                }
                psc[row * PSST + 112 + l16] = 0;
            }
            bf16x8 pa[4];
            #pragma unroll
            for (int kf = 0; kf < 4; kf++)
                pa[kf] = *(const bf16x8*)(psc + l16 * PSST + kf * 32 + quad * 8);
            #pragma unroll
            for (int ntd = 0; ntd < 4; ntd++)
                #pragma unroll
                for (int kf = 0; kf < 4; kf++) {
                    bf16x8 bv = *(const bf16x8*)(V_t + (ntd * 16 + l16) * VTST + kf * 32 + quad * 8);
                    oacc[ntd] = __builtin_amdgcn_mfma_f32_16x16x32_bf16(pa[kf], bv, oacc[ntd], 0, 0, 0);
                }
        }
        #pragma unroll
        for (int ntd = 0; ntd < 4; ntd++)
            #pragma unroll
            for (int r = 0; r < 4; r++) {
                int irow = s * 16 + quad * 4 + r;
                if (irow < 100) {
                    int col = h * 64 + ntd * 16 + l16;
                    int row = b * SS + irow;
                    *PANEL(outp, MM, row, col) = f2bf(oacc[ntd][r]);
                }
            }
    }
}

// ---------------------------------------------------------------------------
__global__ void ln_kernel(const float* __restrict__ x, const float* __restrict__ a,
                          const float* __restrict__ g, const float* __restrict__ bb,
                          unsigned short* __restrict__ outp) {
    int r = blockIdx.x;
    int t = threadIdx.x;
    float4 xv = *(const float4*)(x + (size_t)r * DD + t * 4);
    float4 av = *(const float4*)(a + (size_t)r * DD + t * 4);
    float v0 = xv.x + av.x, v1 = xv.y + av.y, v2 = xv.z + av.z, v3 = xv.w + av.w;
    float sum = v0 + v1 + v2 + v3;
    float sq  = v0 * v0 + v1 * v1 + v2 * v2 + v3 * v3;
    #pragma unroll
    for (int o = 32; o > 0; o >>= 1) {
        sum += __shfl_down(sum, o);
        sq  += __shfl_down(sq, o);
    }
    __shared__ float ls[2], lq[2];
    if ((t & 63) == 0) { ls[t >> 6] = sum; lq[t >> 6] = sq; }
    __syncthreads();
    float S_ = ls[0] + ls[1], Q_ = lq[0] + lq[1];
    float m   = S_ / 512.0f;
    float var = Q_ / 512.0f - m * m;
    float rs  = rsqrtf(var + 1e-5f);
    float4 gv = *(const float4*)(g  + t * 4);
    float4 bv = *(const float4*)(bb + t * 4);
    unsigned short pk[4];
    pk[0] = f2bf((v0 - m) * rs * gv.x + bv.x);
    pk[1] = f2bf((v1 - m) * rs * gv.y + bv.y);
    pk[2] = f2bf((v2 - m) * rs * gv.z + bv.z);
    pk[3] = f2bf((v3 - m) * rs * gv.w + bv.w);
    *(uint2*)PANEL(outp, MM, r, t * 4) = *(uint2*)pk;
}

// ---------------------------------------------------------------------------
__global__ void combine_kernel(float* __restrict__ src, const float* __restrict__ bg,
                               const float* __restrict__ proj,
                               unsigned short* __restrict__ srcbf) {
    int r = blockIdx.x, t = threadIdx.x;
    size_t off = (size_t)r * DD + t * 4;
    float4 s = *(const float4*)(src + off);
    float4 g = *(const float4*)(bg + off);
    float4 p = *(const float4*)(proj + off);
    s.x = s.x * (1.0f - g.x) + p.x * g.x;
    s.y = s.y * (1.0f - g.y) + p.y * g.y;
    s.z = s.z * (1.0f - g.z) + p.z * g.z;
    s.w = s.w * (1.0f - g.w) + p.w * g.w;
    *(float4*)(src + off) = s;
    unsigned short pk[4] = {f2bf(s.x), f2bf(s.y), f2bf(s.z), f2bf(s.w)};
    *(uint2*)PANEL(srcbf, MM, r, t * 4) = *(uint2*)pk;
}

// ---------------------------------------------------------------------------
extern "C" void kernel_launch(void* const* d_in, const int* in_sizes, int n_in,
                              void* d_out, int out_size, void* d_ws, size_t ws_size,
                              hipStream_t stream) {
    const int*   ids     = (const int*)  d_in[0];
    const int*   src_len = (const int*)  d_in[1];
    const float* emb     = (const float*)d_in[2];
    const float* Wq      = (const float*)d_in[3];
    const float* Wkv     = (const float*)d_in[4];
    const float* Wpos    = (const float*)d_in[5];
    const float* Wout    = (const float*)d_in[6];
    const float* u       = (const float*)d_in[7];
    const float* v       = (const float*)d_in[8];
    const float* ng      = (const float*)d_in[9];
    const float* nb      = (const float*)d_in[10];
    const float* p1_w    = (const float*)d_in[11];
    const float* p1_b    = (const float*)d_in[12];
    const float* p2_w    = (const float*)d_in[13];
    const float* p2_b    = (const float*)d_in[14];
    const float* g1_w    = (const float*)d_in[15];
    const float* g1_b    = (const float*)d_in[16];
    const float* g2_w    = (const float*)d_in[17];
    const float* g2_b    = (const float*)d_in[18];

    float* src = (float*)d_out;

    float* ws     = (float*)d_ws;
    float* q      = ws;
    float* t1     = q    + (size_t)MM * DD;
    float* proj   = t1   + (size_t)MM * DD;
    float* bg     = proj + (size_t)MM * DD;
    unsigned short* kpbf  = (unsigned short*)(bg + (size_t)MM * DD);
    unsigned short* srcbf = kpbf  + (size_t)RR * DD;
    unsigned short* netbf = srcbf + (size_t)MM * DD;
    unsigned short* t0p   = netbf + (size_t)MM * DD;
    unsigned short* kvb   = t0p   + (size_t)MM * DD;
    unsigned short* ffb   = kvb   + (size_t)MM * 2 * DD;
    unsigned short* hgb   = ffb   + (size_t)MM * DFFF;
    unsigned short* wq_t   = hgb   + (size_t)MM * DD;
    unsigned short* wkv_t  = wq_t   + 512 * 512;
    unsigned short* wout_t = wkv_t  + 1024 * 512;
    unsigned short* p1_t   = wout_t + 512 * 512;
    unsigned short* p2_t   = p1_t   + 2048 * 512;
    unsigned short* g1_t   = p2_t   + 512 * 2048;
    unsigned short* g2_t   = g1_t   + 512 * 512;

    embed_kernel<<<MM, 128, 0, stream>>>(ids, emb, src, srcbf);
    kpos_kernel<<<RR, DD, 0, stream>>>(Wpos, kpbf);
    wtr_kernel<<<(512*512 +255)/256, 256, 0, stream>>>(Wq,   wq_t,   512, 512);
    wtr_kernel<<<(512*1024+255)/256, 256, 0, stream>>>(Wkv,  wkv_t,  512, 1024);
    wtr_kernel<<<(512*512 +255)/256, 256, 0, stream>>>(Wout, wout_t, 512, 512);
    wtr_kernel<<<(512*2048+255)/256, 256, 0, stream>>>(p1_w, p1_t,   512, 2048);
    wtr_kernel<<<(2048*512+255)/256, 256, 0, stream>>>(p2_w, p2_t,   2048, 512);
    wtr_kernel<<<(512*512 +255)/256, 256, 0, stream>>>(g1_w, g1_t,   512, 512);
    wtr_kernel<<<(512*512 +255)/256, 256, 0, stream>>>(g2_w, g2_t,   512, 512);

    int g64  = mgemm_grid(MM, 512, 64);    // 8*13*8
    int g128k = mgemm_grid(MM, 1024, 128); // kv
    int g128f = mgemm_grid(MM, 2048, 128); // p1

    for (int layer = 0; layer < NLAYERS; layer++) {
        mgemm<0,0,64><<<g64, 256, 0, stream>>>(
            srcbf, wq_t, (const float*)nullptr, q, (unsigned short*)nullptr, MM, 512, 512);
        mgemm<0,2,128><<<g128k, 256, 0, stream>>>(
            srcbf, wkv_t, (const float*)nullptr, (float*)nullptr, kvb, MM, 1024, 512);
        attn_kernel2<<<BB * HH, 256, 0, stream>>>(q, kvb, kpbf, u, v, src_len, t0p);
        mgemm<0,0,64><<<g64, 256, 0, stream>>>(
            t0p, wout_t, (const float*)nullptr, t1, (unsigned short*)nullptr, MM, 512, 512);
        ln_kernel<<<MM, 128, 0, stream>>>(src, t1, ng, nb, netbf);
        mgemm<1,1,128><<<g128f, 256, 0, stream>>>(
            netbf, p1_t, p1_b, (float*)nullptr, ffb, MM, 2048, 512);
        mgemm<2,0,64><<<g64, 256, 0, stream>>>(
            ffb, p2_t, p2_b, proj, (unsigned short*)nullptr, MM, 512, 2048);
        mgemm<1,1,64><<<g64, 256, 0, stream>>>(
            netbf, g1_t, g1_b, (float*)nullptr, hgb, MM, 512, 512);
        mgemm<3,0,64><<<g64, 256, 0, stream>>>(
            hgb, g2_t, g2_b, bg, (unsigned short*)nullptr, MM, 512, 512);
        combine_kernel<<<MM, 128, 0, stream>>>(src, bg, proj, srcbf);
    }
}